// Round 2
// baseline (695.896 us; speedup 1.0000x reference)
//
#include <hip/hip_runtime.h>

typedef unsigned short u16;
typedef __attribute__((ext_vector_type(8))) short short8;
typedef __attribute__((ext_vector_type(4))) float f32x4;
typedef __attribute__((ext_vector_type(4))) unsigned short u16x4;

#define B_  2
#define T_  2048
#define D_  2048
#define NH_ 16
#define HD_ 128
#define QBLK 64
#define KBLK 32

#define MFMA16(a,b,c) __builtin_amdgcn_mfma_f32_16x16x32_bf16((a),(b),(c),0,0,0)

__device__ __forceinline__ float bf2f(u16 h) {
  union { unsigned int u; float f; } v; v.u = ((unsigned int)h) << 16; return v.f;
}
__device__ __forceinline__ u16 f2bf(float f) {
  union { float f; unsigned int u; } v; v.f = f;
  unsigned int r = v.u + 0x7FFFu + ((v.u >> 16) & 1u);
  return (u16)(r >> 16);
}

// global -> LDS direct copy, 16B per lane. dst must be wave-uniform.
__device__ __forceinline__ void gll16(void* lds, const void* g) {
  __builtin_amdgcn_global_load_lds(
      (const __attribute__((address_space(1))) unsigned int*)(size_t)(g),
      (__attribute__((address_space(3))) unsigned int*)(unsigned int)(size_t)(lds),
      16, 0, 0);
}

// ---------------- x fp32 -> bf16 hi + lo residual planes ----------------
__global__ __launch_bounds__(256)
void cast_split_x_kernel(const float* __restrict__ X, u16* __restrict__ Xh,
                         u16* __restrict__ Xl) {
  size_t i = ((size_t)blockIdx.x * 256 + threadIdx.x) * 4;
  float4 v = *(const float4*)(X + i);
  u16x4 h, l;
  h.x = f2bf(v.x); l.x = f2bf(v.x - bf2f(h.x));
  h.y = f2bf(v.y); l.y = f2bf(v.y - bf2f(h.y));
  h.z = f2bf(v.z); l.z = f2bf(v.z - bf2f(h.z));
  h.w = f2bf(v.w); l.w = f2bf(v.w - bf2f(h.w));
  *(u16x4*)(Xh + i) = h;
  *(u16x4*)(Xl + i) = l;
}

// -------- W fp32 [k][n] -> bf16 Wt [n][k], hi(+lo for q,k) planes --------
__global__ __launch_bounds__(256)
void wt_split_kernel(const float* __restrict__ Wq, const float* __restrict__ Wk,
                     const float* __restrict__ Wv,
                     u16* __restrict__ Wqh, u16* __restrict__ Wql,
                     u16* __restrict__ Wkh, u16* __restrict__ Wkl,
                     u16* __restrict__ Wvh) {
  __shared__ float tile[32][33];
  const int z = blockIdx.z;
  const float* W = z == 0 ? Wq : (z == 1 ? Wk : Wv);
  u16* Oh = z == 0 ? Wqh : (z == 1 ? Wkh : Wvh);
  u16* Ol = z == 0 ? Wql : Wkl;  // unused for z==2
  int k0 = blockIdx.x * 32, n0 = blockIdx.y * 32;
  int tx = threadIdx.x & 31, ty = threadIdx.x >> 5;
#pragma unroll
  for (int s = 0; s < 4; ++s)
    tile[ty + s * 8][tx] = W[(size_t)(k0 + ty + s * 8) * 2048 + n0 + tx];
  __syncthreads();
#pragma unroll
  for (int s = 0; s < 4; ++s) {
    float w = tile[tx][ty + s * 8];
    u16 h = f2bf(w);
    size_t o = (size_t)(n0 + ty + s * 8) * 2048 + k0 + tx;
    Oh[o] = h;
    if (z < 2) Ol[o] = f2bf(w - bf2f(h));
  }
}

// ---------------- RoPE table: cos/sin [T][64] fp32 ----------------
__global__ void rope_table_kernel(float* __restrict__ cosT, float* __restrict__ sinT) {
  int t = blockIdx.x, d = threadIdx.x;  // 64 threads
  float invf = exp2f(-(float)d * (13.287712379549449f / 64.f));  // 10000^(-d/64)
  float fr = (float)t * invf;
  cosT[t * 64 + d] = cosf(fr);
  sinT[t * 64 + d] = sinf(fr);
}

// ---------------- lambda scalar ----------------
__global__ void lambda_kernel(const float* __restrict__ lq1, const float* __restrict__ lk1,
                              const float* __restrict__ lq2, const float* __restrict__ lk2,
                              float* __restrict__ lam) {
  int l = threadIdx.x;  // 64
  float a = lq1[l] * lk1[l];
  float b = lq2[l] * lk2[l];
#pragma unroll
  for (int off = 1; off < 64; off <<= 1) { a += __shfl_xor(a, off); b += __shfl_xor(b, off); }
  if (l == 0) lam[0] = expf(a) - expf(b) + 0.2f;
}

// ------ split GEMM: C = (Xh+Xl)(4096x2048) * (Wh+Wl)^T -> fp32 (q,k) ------
// 3-term: hh + hl + lh. 128x128 tile, 4 waves 2x2, BK=32.
__global__ __launch_bounds__(256)
void gemm_split_kernel(const u16* __restrict__ Ah, const u16* __restrict__ Al,
                       const u16* __restrict__ Wqh, const u16* __restrict__ Wql,
                       const u16* __restrict__ Wkh, const u16* __restrict__ Wkl,
                       float* __restrict__ Qf, float* __restrict__ Kf) {
  __shared__ u16 Ash[128 * 32];
  __shared__ u16 Asl[128 * 32];
  __shared__ u16 Bsh[128 * 32];
  __shared__ u16 Bsl[128 * 32];
  const int bn = blockIdx.x, bm = blockIdx.y, z = blockIdx.z;
  const u16* Bh = z ? Wkh : Wqh;
  const u16* Bl = z ? Wkl : Wql;
  float* C = z ? Kf : Qf;
  const int tid = threadIdx.x;
  const int w = tid >> 6, l = tid & 63;
  const int li = l & 15, lg = l >> 4;
  const int wr = w >> 1, wc = w & 1;

  f32x4 acc[4][4] = {};

  // staging geometry: chunk c = w*2+i, i in 0..1 (1024B each, 8KB per tile)
  int rowc[2], csc[2];
#pragma unroll
  for (int i = 0; i < 2; ++i) {
    int o = (w * 2 + i) * 1024 + l * 16;
    rowc[i] = o >> 6;
    csc[i] = ((o >> 4) & 3) ^ (rowc[i] & 3);
  }
  const u16* sAh[2]; const u16* sAl[2]; const u16* sBh[2]; const u16* sBl[2];
  char* dA[2]; char* dAl2[2]; char* dB[2]; char* dBl2[2];
#pragma unroll
  for (int i = 0; i < 2; ++i) {
    size_t ao = (size_t)(bm * 128 + rowc[i]) * 2048 + csc[i] * 8;
    size_t bo = (size_t)(bn * 128 + rowc[i]) * 2048 + csc[i] * 8;
    sAh[i] = Ah + ao; sAl[i] = Al + ao;
    sBh[i] = Bh + bo; sBl[i] = Bl + bo;
    dA[i]   = (char*)Ash + (w * 2 + i) * 1024;
    dAl2[i] = (char*)Asl + (w * 2 + i) * 1024;
    dB[i]   = (char*)Bsh + (w * 2 + i) * 1024;
    dBl2[i] = (char*)Bsl + (w * 2 + i) * 1024;
  }

  for (int kt = 0; kt < 64; ++kt) {
    __syncthreads();
#pragma unroll
    for (int i = 0; i < 2; ++i) {
      gll16(dA[i],   sAh[i] + kt * 32);
      gll16(dAl2[i], sAl[i] + kt * 32);
      gll16(dB[i],   sBh[i] + kt * 32);
      gll16(dBl2[i], sBl[i] + kt * 32);
    }
    __syncthreads();
    short8 ah[4], al[4], bh[4], bl[4];
#pragma unroll
    for (int mi = 0; mi < 4; ++mi) {
      int row = wr * 64 + mi * 16 + li;
      int ch = lg ^ (row & 3);
      ah[mi] = *(const short8*)((const char*)Ash + row * 64 + ch * 16);
      al[mi] = *(const short8*)((const char*)Asl + row * 64 + ch * 16);
    }
#pragma unroll
    for (int ni = 0; ni < 4; ++ni) {
      int row = wc * 64 + ni * 16 + li;
      int ch = lg ^ (row & 3);
      bh[ni] = *(const short8*)((const char*)Bsh + row * 64 + ch * 16);
      bl[ni] = *(const short8*)((const char*)Bsl + row * 64 + ch * 16);
    }
#pragma unroll
    for (int mi = 0; mi < 4; ++mi)
#pragma unroll
      for (int ni = 0; ni < 4; ++ni) {
        acc[mi][ni] = MFMA16(ah[mi], bh[ni], acc[mi][ni]);
        acc[mi][ni] = MFMA16(ah[mi], bl[ni], acc[mi][ni]);
        acc[mi][ni] = MFMA16(al[mi], bh[ni], acc[mi][ni]);
      }
  }
#pragma unroll
  for (int mi = 0; mi < 4; ++mi)
#pragma unroll
    for (int ni = 0; ni < 4; ++ni) {
      int n = bn * 128 + wc * 64 + ni * 16 + li;
#pragma unroll
      for (int r = 0; r < 4; ++r) {
        int m = bm * 128 + wr * 64 + mi * 16 + lg * 4 + r;
        C[(size_t)m * 2048 + n] = acc[mi][ni][r];
      }
    }
}

// ------------- plain GEMM for V: Xh * Wvh^T -> bf16 -------------
__global__ __launch_bounds__(256)
void gemm_v_kernel(const u16* __restrict__ Xb, const u16* __restrict__ Bw,
                   u16* __restrict__ C) {
  __shared__ u16 As[128 * 32];
  __shared__ u16 Bs[128 * 32];
  const int bn = blockIdx.x, bm = blockIdx.y;
  const int tid = threadIdx.x;
  const int w = tid >> 6, l = tid & 63;
  const int li = l & 15, lg = l >> 4;
  const int wr = w >> 1, wc = w & 1;

  f32x4 acc[4][4] = {};

  const int o0 = (w * 2 + 0) * 1024 + l * 16;
  const int o1 = (w * 2 + 1) * 1024 + l * 16;
  const int rA0 = o0 >> 6, rA1 = o1 >> 6;
  const int cs0 = ((o0 >> 4) & 3) ^ (rA0 & 3);
  const int cs1 = ((o1 >> 4) & 3) ^ (rA1 & 3);
  const u16* srcA0 = Xb + (size_t)(bm * 128 + rA0) * 2048 + cs0 * 8;
  const u16* srcA1 = Xb + (size_t)(bm * 128 + rA1) * 2048 + cs1 * 8;
  const u16* srcB0 = Bw + (size_t)(bn * 128 + rA0) * 2048 + cs0 * 8;
  const u16* srcB1 = Bw + (size_t)(bn * 128 + rA1) * 2048 + cs1 * 8;
  char* dstA0 = (char*)As + (w * 2 + 0) * 1024;
  char* dstA1 = (char*)As + (w * 2 + 1) * 1024;
  char* dstB0 = (char*)Bs + (w * 2 + 0) * 1024;
  char* dstB1 = (char*)Bs + (w * 2 + 1) * 1024;

  for (int kt = 0; kt < 64; ++kt) {
    __syncthreads();
    gll16(dstA0, srcA0 + kt * 32);
    gll16(dstA1, srcA1 + kt * 32);
    gll16(dstB0, srcB0 + kt * 32);
    gll16(dstB1, srcB1 + kt * 32);
    __syncthreads();
    short8 af[4], bfr[4];
#pragma unroll
    for (int mi = 0; mi < 4; ++mi) {
      int row = wr * 64 + mi * 16 + li;
      int ch = lg ^ (row & 3);
      af[mi] = *(const short8*)((const char*)As + row * 64 + ch * 16);
    }
#pragma unroll
    for (int ni = 0; ni < 4; ++ni) {
      int row = wc * 64 + ni * 16 + li;
      int ch = lg ^ (row & 3);
      bfr[ni] = *(const short8*)((const char*)Bs + row * 64 + ch * 16);
    }
#pragma unroll
    for (int mi = 0; mi < 4; ++mi)
#pragma unroll
      for (int ni = 0; ni < 4; ++ni)
        acc[mi][ni] = MFMA16(af[mi], bfr[ni], acc[mi][ni]);
  }
#pragma unroll
  for (int mi = 0; mi < 4; ++mi)
#pragma unroll
    for (int ni = 0; ni < 4; ++ni) {
      int n = bn * 128 + wc * 64 + ni * 16 + li;
#pragma unroll
      for (int r = 0; r < 4; ++r) {
        int m = bm * 128 + wr * 64 + mi * 16 + lg * 4 + r;
        C[(size_t)m * 2048 + n] = f2bf(acc[mi][ni][r]);
      }
    }
}

// ---- RMSNorm + RoPE (+ log-pos scale for Q) in fp32, out hi/lo bf16 ----
__global__ __launch_bounds__(256)
void qk_process_kernel(const float* __restrict__ Qf, const float* __restrict__ Kf,
                       const float* __restrict__ cosT, const float* __restrict__ sinT,
                       const float* __restrict__ scaler,
                       u16* __restrict__ Qph, u16* __restrict__ Qpl,
                       u16* __restrict__ Kph, u16* __restrict__ Kpl) {
  const int r = blockIdx.x * 4 + (threadIdx.x >> 6);
  const int l = threadIdx.x & 63;
  const bool isQ = (blockIdx.y == 0);
  const float* src = isQ ? Qf : Kf;
  u16* dsth = isQ ? Qph : Kph;
  u16* dstl = isQ ? Qpl : Kpl;
  const int b = r >> 15;
  const int t = (r >> 4) & 2047;
  const int h = r & 15;
  float v1 = src[(size_t)r * 128 + l];
  float v2 = src[(size_t)r * 128 + l + 64];
  float ss = v1 * v1 + v2 * v2;
#pragma unroll
  for (int off = 1; off < 64; off <<= 1) ss += __shfl_xor(ss, off);
  float rr = rsqrtf(ss * (1.f / 128.f) + 1.1920929e-07f);
  float c = cosT[t * 64 + l], s = sinT[t * 64 + l];
  float n1 = v1 * rr, n2 = v2 * rr;
  float o1 = n1 * c + n2 * s;
  float o2 = n2 * c - n1 * s;
  if (isQ) {
    float mlt = scaler[h] * logf((float)(t + 1));
    o1 *= mlt; o2 *= mlt;
  }
  size_t orow = ((size_t)(b * 16 + h) * 2048 + t) * 128;
  u16 h1 = f2bf(o1), h2 = f2bf(o2);
  dsth[orow + l] = h1;
  dsth[orow + l + 64] = h2;
  dstl[orow + l] = f2bf(o1 - bf2f(h1));
  dstl[orow + l + 64] = f2bf(o2 - bf2f(h2));
}

// ---------------- V: [b][t][hv*256+dv] bf16 -> Vt [b*8+hv][dv][t] ----------------
__global__ __launch_bounds__(256)
void v_transpose_kernel(const u16* __restrict__ Vg, u16* __restrict__ Vt) {
  __shared__ u16 tile[32][34];
  const int bz = blockIdx.z;           // b*8+hv
  const int b = bz >> 3, hv = bz & 7;
  const int t0 = blockIdx.x * 32, dv0 = blockIdx.y * 32;
  const int tx = threadIdx.x & 31, ty = threadIdx.x >> 5;
#pragma unroll
  for (int s = 0; s < 4; ++s) {
    int t = t0 + ty + s * 8;
    tile[ty + s * 8][tx] = Vg[(size_t)(b * 2048 + t) * 2048 + hv * 256 + dv0 + tx];
  }
  __syncthreads();
#pragma unroll
  for (int s = 0; s < 4; ++s) {
    int dv = dv0 + ty + s * 8;
    Vt[((size_t)bz * 256 + dv) * 2048 + t0 + tx] = tile[tx][ty + s * 8];
  }
}

// ---------------- causal flash attention (split-bf16 QK^T) ----------------
// grid: x = T/QBLK (32), y = B*NH (32). block 256 (4 waves, 16 q-rows each).
__global__ __launch_bounds__(256)
void attn_kernel(const u16* __restrict__ Qph, const u16* __restrict__ Qpl,
                 const u16* __restrict__ Kph, const u16* __restrict__ Kpl,
                 const u16* __restrict__ Vt,
                 float* __restrict__ Y1, float* __restrict__ Y2) {
  __shared__ u16 Ksh[KBLK * 128];  // [key][feat] hi, chunk^(key&7) swizzle
  __shared__ u16 Ksl[KBLK * 128];  // lo plane
  __shared__ u16 Vs[256 * KBLK];   // [dv][key],  chunk^(dv&3) swizzle
  __shared__ u16 Ps[4][16 * 48];   // per-wave P [qrow][key], stride 48
  const int qt = blockIdx.x;
  const int bh = blockIdx.y;
  const int b = bh >> 4, h = bh & 15;
  const int grp = h >> 3, hv = h & 7;
  const u16* QhP = Qph + (size_t)bh * (T_ * HD_);
  const u16* QlP = Qpl + (size_t)bh * (T_ * HD_);
  const u16* KhP = Kph + (size_t)bh * (T_ * HD_);
  const u16* KlP = Kpl + (size_t)bh * (T_ * HD_);
  const u16* Vh = Vt + (size_t)(b * 8 + hv) * (256 * T_);
  float* Yout = (grp ? Y2 : Y1) + ((size_t)(b * 8 + hv) * T_ + qt * QBLK) * 256;

  const int tid = threadIdx.x;
  const int w = tid >> 6, l = tid & 63;
  const int li = l & 15, lg = l >> 4;
  const int q0 = qt * QBLK + w * 16;

  short8 qfh[4], qfl[4];
  {
    const u16* qrowh = QhP + (size_t)(q0 + li) * 128;
    const u16* qrowl = QlP + (size_t)(q0 + li) * 128;
#pragma unroll
    for (int kc = 0; kc < 4; ++kc) {
      qfh[kc] = *(const short8*)(qrowh + kc * 32 + lg * 8);
      qfl[kc] = *(const short8*)(qrowl + kc * 32 + lg * 8);
    }
  }
  f32x4 acc[16] = {};
  float m[4], se[4];
#pragma unroll
  for (int r = 0; r < 4; ++r) { m[r] = -1e30f; se[r] = 0.f; }

  const int nkv = (qt + 1) * QBLK / KBLK;
  for (int kv = 0; kv < nkv; ++kv) {
    const int kv0 = kv * KBLK;
    __syncthreads();
#pragma unroll
    for (int i = 0; i < 2; ++i) {
      int o = (w * 2 + i) * 1024 + l * 16;
      int row = o >> 8;
      int cs = ((o >> 4) & 15) ^ (row & 7);
      gll16((char*)Ksh + (w * 2 + i) * 1024, KhP + (size_t)(kv0 + row) * 128 + cs * 8);
      gll16((char*)Ksl + (w * 2 + i) * 1024, KlP + (size_t)(kv0 + row) * 128 + cs * 8);
    }
#pragma unroll
    for (int i = 0; i < 4; ++i) {
      int o = (w * 4 + i) * 1024 + l * 16;
      int dv = o >> 6;
      int cs = ((o >> 4) & 3) ^ (dv & 3);
      gll16((char*)Vs + (w * 4 + i) * 1024, Vh + (size_t)dv * T_ + kv0 + cs * 8);
    }
    __syncthreads();
    if (kv0 <= q0 + 15) {
      f32x4 s0 = {}, s1 = {};
#pragma unroll
      for (int kc = 0; kc < 4; ++kc) {
        int ch = kc * 4 + lg;
        int off0 = li * 256 + ((ch ^ (li & 7)) * 16);
        int off1 = (li + 16) * 256 + ((ch ^ (li & 7)) * 16);
        const short8 k0h = *(const short8*)((const char*)Ksh + off0);
        const short8 k1h = *(const short8*)((const char*)Ksh + off1);
        const short8 k0l = *(const short8*)((const char*)Ksl + off0);
        const short8 k1l = *(const short8*)((const char*)Ksl + off1);
        s0 = MFMA16(qfh[kc], k0h, s0);
        s0 = MFMA16(qfh[kc], k0l, s0);
        s0 = MFMA16(qfl[kc], k0h, s0);
        s1 = MFMA16(qfh[kc], k1h, s1);
        s1 = MFMA16(qfh[kc], k1l, s1);
        s1 = MFMA16(qfl[kc], k1h, s1);
      }
      const float scale = 0.08838834764831845f;  // 1/sqrt(128)
      float corr[4];
#pragma unroll
      for (int r = 0; r < 4; ++r) {
        const int qr = q0 + lg * 4 + r;
        float v0 = s0[r] * scale, v1 = s1[r] * scale;
        if (kv0 + li > qr) v0 = -1e30f;
        if (kv0 + 16 + li > qr) v1 = -1e30f;
        float tmx = fmaxf(v0, v1);
        tmx = fmaxf(tmx, __shfl_xor(tmx, 1));
        tmx = fmaxf(tmx, __shfl_xor(tmx, 2));
        tmx = fmaxf(tmx, __shfl_xor(tmx, 4));
        tmx = fmaxf(tmx, __shfl_xor(tmx, 8));
        const float mn = fmaxf(m[r], tmx);
        corr[r] = exp2f((m[r] - mn) * 1.4426950408889634f);
        float p0 = exp2f((v0 - mn) * 1.4426950408889634f);
        float p1 = exp2f((v1 - mn) * 1.4426950408889634f);
        m[r] = mn;
        float rs = p0 + p1;
        rs += __shfl_xor(rs, 1);
        rs += __shfl_xor(rs, 2);
        rs += __shfl_xor(rs, 4);
        rs += __shfl_xor(rs, 8);
        se[r] = se[r] * corr[r] + rs;
        s0[r] = p0; s1[r] = p1;
      }
#pragma unroll
      for (int nt = 0; nt < 16; ++nt) {
        f32x4 a = acc[nt];
        a[0] *= corr[0]; a[1] *= corr[1]; a[2] *= corr[2]; a[3] *= corr[3];
        acc[nt] = a;
      }
      u16* Pw = &Ps[w][0];
#pragma unroll
      for (int r = 0; r < 4; ++r) {
        Pw[(lg * 4 + r) * 48 + li] = f2bf(s0[r]);
        Pw[(lg * 4 + r) * 48 + 16 + li] = f2bf(s1[r]);
      }
      const short8 pa = *(const short8*)((const char*)Pw + li * 96 + lg * 16);
#pragma unroll
      for (int nt = 0; nt < 16; ++nt) {
        const int dv = nt * 16 + li;
        const int ch = lg ^ (dv & 3);
        const short8 vf = *(const short8*)((const char*)Vs + dv * 64 + ch * 16);
        acc[nt] = MFMA16(pa, vf, acc[nt]);
      }
    }
  }
  float inv[4];
#pragma unroll
  for (int r = 0; r < 4; ++r) inv[r] = 1.0f / se[r];
#pragma unroll
  for (int nt = 0; nt < 16; ++nt)
#pragma unroll
    for (int r = 0; r < 4; ++r)
      Yout[(size_t)(w * 16 + lg * 4 + r) * 256 + nt * 16 + li] = acc[nt][r] * inv[r];
}

// ---------------- combine: y = y1 - lambda*y2, layout back ----------------
__global__ __launch_bounds__(256)
void combine_kernel(const float* __restrict__ Y1, const float* __restrict__ Y2,
                    const float* __restrict__ lamp, float* __restrict__ out) {
  size_t f = ((size_t)blockIdx.x * 256 + threadIdx.x) * 4;
  int dv = (int)(f & 255);
  int hv = (int)((f >> 8) & 7);
  size_t bt = f >> 11;
  int t = (int)(bt & 2047);
  int b = (int)(bt >> 11);
  const float lam = lamp[0];
  size_t yi = ((size_t)(b * 8 + hv) * 2048 + t) * 256 + dv;
  float4 a = *(const float4*)(Y1 + yi);
  float4 c = *(const float4*)(Y2 + yi);
  float4 o;
  o.x = a.x - lam * c.x; o.y = a.y - lam * c.y;
  o.z = a.z - lam * c.z; o.w = a.w - lam * c.w;
  *(float4*)(out + f) = o;
}

// ---------------- launch ----------------
extern "C" void kernel_launch(void* const* d_in, const int* in_sizes, int n_in,
                              void* d_out, int out_size, void* d_ws, size_t ws_size,
                              hipStream_t stream) {
  const float* x   = (const float*)d_in[0];
  const float* Wq  = (const float*)d_in[1];
  const float* Wk  = (const float*)d_in[2];
  const float* Wv  = (const float*)d_in[3];
  const float* lq1 = (const float*)d_in[4];
  const float* lk1 = (const float*)d_in[5];
  const float* lq2 = (const float*)d_in[6];
  const float* lk2 = (const float*)d_in[7];
  const float* scl = (const float*)d_in[8];
  float* out = (float*)d_out;

  char* ws = (char*)d_ws;
  // phase-1 buffers
  u16*  Xh   = (u16*)(ws + 0);            // 16 MB  (later aliased by Qph)
  u16*  Xl   = (u16*)(ws + 16777216);     // 16 MB  (later aliased by Qpl)
  u16*  Wqh  = (u16*)(ws + 33554432);     // 8 MB   (later aliased by Kph)
  u16*  Wql  = (u16*)(ws + 41943040);     // 8 MB
  u16*  Wkh  = (u16*)(ws + 50331648);     // 8 MB   (later aliased by Kpl)
  u16*  Wkl  = (u16*)(ws + 58720256);     // 8 MB
  u16*  Wvh  = (u16*)(ws + 67108864);     // 8 MB
  float* Qf  = (float*)(ws + 75497472);   // 32 MB  (later aliased by Y1)
  float* Kf  = (float*)(ws + 109051904);  // 32 MB  (later aliased by Y2)
  u16*  Vg   = (u16*)(ws + 142606336);    // 16 MB
  u16*  Vt   = (u16*)(ws + 159383552);    // 16 MB
  float* cosT = (float*)(ws + 176160768); // 0.5 MB
  float* sinT = (float*)(ws + 176685056); // 0.5 MB
  float* lam  = (float*)(ws + 177209344); // 4 B
  // phase-2 aliases (dead-buffer reuse; same-stream ordering makes this safe)
  u16*  Qph = (u16*)(ws + 0);
  u16*  Qpl = (u16*)(ws + 16777216);
  u16*  Kph = (u16*)(ws + 33554432);
  u16*  Kpl = (u16*)(ws + 50331648);
  float* Y1 = (float*)(ws + 75497472);
  float* Y2 = (float*)(ws + 109051904);

  cast_split_x_kernel<<<8192, 256, 0, stream>>>(x, Xh, Xl);
  wt_split_kernel<<<dim3(64, 64, 3), 256, 0, stream>>>(Wq, Wk, Wv, Wqh, Wql, Wkh, Wkl, Wvh);
  rope_table_kernel<<<2048, 64, 0, stream>>>(cosT, sinT);
  lambda_kernel<<<1, 64, 0, stream>>>(lq1, lk1, lq2, lk2, lam);
  gemm_split_kernel<<<dim3(16, 32, 2), 256, 0, stream>>>(Xh, Xl, Wqh, Wql, Wkh, Wkl, Qf, Kf);
  gemm_v_kernel<<<dim3(16, 32), 256, 0, stream>>>(Xh, Wvh, Vg);
  qk_process_kernel<<<dim3(16384, 2), 256, 0, stream>>>(Qf, Kf, cosT, sinT, scl, Qph, Qpl, Kph, Kpl);
  v_transpose_kernel<<<dim3(64, 8, 16), 256, 0, stream>>>(Vg, Vt);
  attn_kernel<<<dim3(32, 32), 256, 0, stream>>>(Qph, Qpl, Kph, Kpl, Vt, Y1, Y2);
  combine_kernel<<<8192, 256, 0, stream>>>(Y1, Y2, lam, out);
}

// Round 3
// 622.496 us; speedup vs baseline: 1.1179x; 1.1179x over previous
//
#include <hip/hip_runtime.h>

typedef unsigned short u16;
typedef __attribute__((ext_vector_type(8))) short short8;
typedef __attribute__((ext_vector_type(4))) float f32x4;
typedef __attribute__((ext_vector_type(4))) unsigned short u16x4;

#define B_  2
#define T_  2048
#define D_  2048
#define NH_ 16
#define HD_ 128
#define QBLK 64
#define KBLK 32

#define MFMA16(a,b,c) __builtin_amdgcn_mfma_f32_16x16x32_bf16((a),(b),(c),0,0,0)

__device__ __forceinline__ float bf2f(u16 h) {
  union { unsigned int u; float f; } v; v.u = ((unsigned int)h) << 16; return v.f;
}
__device__ __forceinline__ u16 f2bf(float f) {
  union { float f; unsigned int u; } v; v.f = f;
  unsigned int r = v.u + 0x7FFFu + ((v.u >> 16) & 1u);
  return (u16)(r >> 16);
}

// global -> LDS direct copy, 16B per lane. dst must be wave-uniform.
__device__ __forceinline__ void gll16(void* lds, const void* g) {
  __builtin_amdgcn_global_load_lds(
      (const __attribute__((address_space(1))) unsigned int*)(size_t)(g),
      (__attribute__((address_space(3))) unsigned int*)(unsigned int)(size_t)(lds),
      16, 0, 0);
}

// ---------------- x fp32 -> bf16 hi + lo residual planes ----------------
__global__ __launch_bounds__(256)
void cast_split_x_kernel(const float* __restrict__ X, u16* __restrict__ Xh,
                         u16* __restrict__ Xl) {
  size_t i = ((size_t)blockIdx.x * 256 + threadIdx.x) * 4;
  float4 v = *(const float4*)(X + i);
  u16x4 h, l;
  h.x = f2bf(v.x); l.x = f2bf(v.x - bf2f(h.x));
  h.y = f2bf(v.y); l.y = f2bf(v.y - bf2f(h.y));
  h.z = f2bf(v.z); l.z = f2bf(v.z - bf2f(h.z));
  h.w = f2bf(v.w); l.w = f2bf(v.w - bf2f(h.w));
  *(u16x4*)(Xh + i) = h;
  *(u16x4*)(Xl + i) = l;
}

// -------- W fp32 [k][n] -> bf16 Wt [n][k], hi(+lo for q,k) planes --------
__global__ __launch_bounds__(256)
void wt_split_kernel(const float* __restrict__ Wq, const float* __restrict__ Wk,
                     const float* __restrict__ Wv,
                     u16* __restrict__ Wqh, u16* __restrict__ Wql,
                     u16* __restrict__ Wkh, u16* __restrict__ Wkl,
                     u16* __restrict__ Wvh) {
  __shared__ float tile[32][33];
  const int z = blockIdx.z;
  const float* W = z == 0 ? Wq : (z == 1 ? Wk : Wv);
  u16* Oh = z == 0 ? Wqh : (z == 1 ? Wkh : Wvh);
  u16* Ol = z == 0 ? Wql : Wkl;  // unused for z==2
  int k0 = blockIdx.x * 32, n0 = blockIdx.y * 32;
  int tx = threadIdx.x & 31, ty = threadIdx.x >> 5;
#pragma unroll
  for (int s = 0; s < 4; ++s)
    tile[ty + s * 8][tx] = W[(size_t)(k0 + ty + s * 8) * 2048 + n0 + tx];
  __syncthreads();
#pragma unroll
  for (int s = 0; s < 4; ++s) {
    float w = tile[tx][ty + s * 8];
    u16 h = f2bf(w);
    size_t o = (size_t)(n0 + ty + s * 8) * 2048 + k0 + tx;
    Oh[o] = h;
    if (z < 2) Ol[o] = f2bf(w - bf2f(h));
  }
}

// ---------------- RoPE table: cos/sin [T][64] fp32 ----------------
__global__ void rope_table_kernel(float* __restrict__ cosT, float* __restrict__ sinT) {
  int t = blockIdx.x, d = threadIdx.x;  // 64 threads
  float invf = exp2f(-(float)d * (13.287712379549449f / 64.f));  // 10000^(-d/64)
  float fr = (float)t * invf;
  cosT[t * 64 + d] = cosf(fr);
  sinT[t * 64 + d] = sinf(fr);
}

// ---------------- lambda scalar ----------------
__global__ void lambda_kernel(const float* __restrict__ lq1, const float* __restrict__ lk1,
                              const float* __restrict__ lq2, const float* __restrict__ lk2,
                              float* __restrict__ lam) {
  int l = threadIdx.x;  // 64
  float a = lq1[l] * lk1[l];
  float b = lq2[l] * lk2[l];
#pragma unroll
  for (int off = 1; off < 64; off <<= 1) { a += __shfl_xor(a, off); b += __shfl_xor(b, off); }
  if (l == 0) lam[0] = expf(a) - expf(b) + 0.2f;
}

// ------ split GEMM: C = (Xh+Xl)(4096x2048) * (Wh+Wl)^T -> fp32 (q,k) ------
// 3-term: hh + hl + lh. 128x128 tile, 4 waves 2x2, BK=32.
__global__ __launch_bounds__(256)
void gemm_split_kernel(const u16* __restrict__ Ah, const u16* __restrict__ Al,
                       const u16* __restrict__ Wqh, const u16* __restrict__ Wql,
                       const u16* __restrict__ Wkh, const u16* __restrict__ Wkl,
                       float* __restrict__ Qf, float* __restrict__ Kf) {
  __shared__ u16 Ash[128 * 32];
  __shared__ u16 Asl[128 * 32];
  __shared__ u16 Bsh[128 * 32];
  __shared__ u16 Bsl[128 * 32];
  const int bn = blockIdx.x, bm = blockIdx.y, z = blockIdx.z;
  const u16* Bh = z ? Wkh : Wqh;
  const u16* Bl = z ? Wkl : Wql;
  float* C = z ? Kf : Qf;
  const int tid = threadIdx.x;
  const int w = tid >> 6, l = tid & 63;
  const int li = l & 15, lg = l >> 4;
  const int wr = w >> 1, wc = w & 1;

  f32x4 acc[4][4] = {};

  // staging geometry: chunk c = w*2+i, i in 0..1 (1024B each, 8KB per tile)
  int rowc[2], csc[2];
#pragma unroll
  for (int i = 0; i < 2; ++i) {
    int o = (w * 2 + i) * 1024 + l * 16;
    rowc[i] = o >> 6;
    csc[i] = ((o >> 4) & 3) ^ (rowc[i] & 3);
  }
  const u16* sAh[2]; const u16* sAl[2]; const u16* sBh[2]; const u16* sBl[2];
  char* dA[2]; char* dAl2[2]; char* dB[2]; char* dBl2[2];
#pragma unroll
  for (int i = 0; i < 2; ++i) {
    size_t ao = (size_t)(bm * 128 + rowc[i]) * 2048 + csc[i] * 8;
    size_t bo = (size_t)(bn * 128 + rowc[i]) * 2048 + csc[i] * 8;
    sAh[i] = Ah + ao; sAl[i] = Al + ao;
    sBh[i] = Bh + bo; sBl[i] = Bl + bo;
    dA[i]   = (char*)Ash + (w * 2 + i) * 1024;
    dAl2[i] = (char*)Asl + (w * 2 + i) * 1024;
    dB[i]   = (char*)Bsh + (w * 2 + i) * 1024;
    dBl2[i] = (char*)Bsl + (w * 2 + i) * 1024;
  }

  for (int kt = 0; kt < 64; ++kt) {
    __syncthreads();
#pragma unroll
    for (int i = 0; i < 2; ++i) {
      gll16(dA[i],   sAh[i] + kt * 32);
      gll16(dAl2[i], sAl[i] + kt * 32);
      gll16(dB[i],   sBh[i] + kt * 32);
      gll16(dBl2[i], sBl[i] + kt * 32);
    }
    __syncthreads();
    short8 ah[4], al[4], bh[4], bl[4];
#pragma unroll
    for (int mi = 0; mi < 4; ++mi) {
      int row = wr * 64 + mi * 16 + li;
      int ch = lg ^ (row & 3);
      ah[mi] = *(const short8*)((const char*)Ash + row * 64 + ch * 16);
      al[mi] = *(const short8*)((const char*)Asl + row * 64 + ch * 16);
    }
#pragma unroll
    for (int ni = 0; ni < 4; ++ni) {
      int row = wc * 64 + ni * 16 + li;
      int ch = lg ^ (row & 3);
      bh[ni] = *(const short8*)((const char*)Bsh + row * 64 + ch * 16);
      bl[ni] = *(const short8*)((const char*)Bsl + row * 64 + ch * 16);
    }
#pragma unroll
    for (int mi = 0; mi < 4; ++mi)
#pragma unroll
      for (int ni = 0; ni < 4; ++ni) {
        acc[mi][ni] = MFMA16(ah[mi], bh[ni], acc[mi][ni]);
        acc[mi][ni] = MFMA16(ah[mi], bl[ni], acc[mi][ni]);
        acc[mi][ni] = MFMA16(al[mi], bh[ni], acc[mi][ni]);
      }
  }
#pragma unroll
  for (int mi = 0; mi < 4; ++mi)
#pragma unroll
    for (int ni = 0; ni < 4; ++ni) {
      int n = bn * 128 + wc * 64 + ni * 16 + li;
#pragma unroll
      for (int r = 0; r < 4; ++r) {
        int m = bm * 128 + wr * 64 + mi * 16 + lg * 4 + r;
        C[(size_t)m * 2048 + n] = acc[mi][ni][r];
      }
    }
}

// ------------- plain GEMM for V: Xh * Wvh^T -> bf16 -------------
__global__ __launch_bounds__(256)
void gemm_v_kernel(const u16* __restrict__ Xb, const u16* __restrict__ Bw,
                   u16* __restrict__ C) {
  __shared__ u16 As[128 * 32];
  __shared__ u16 Bs[128 * 32];
  const int bn = blockIdx.x, bm = blockIdx.y;
  const int tid = threadIdx.x;
  const int w = tid >> 6, l = tid & 63;
  const int li = l & 15, lg = l >> 4;
  const int wr = w >> 1, wc = w & 1;

  f32x4 acc[4][4] = {};

  const int o0 = (w * 2 + 0) * 1024 + l * 16;
  const int o1 = (w * 2 + 1) * 1024 + l * 16;
  const int rA0 = o0 >> 6, rA1 = o1 >> 6;
  const int cs0 = ((o0 >> 4) & 3) ^ (rA0 & 3);
  const int cs1 = ((o1 >> 4) & 3) ^ (rA1 & 3);
  const u16* srcA0 = Xb + (size_t)(bm * 128 + rA0) * 2048 + cs0 * 8;
  const u16* srcA1 = Xb + (size_t)(bm * 128 + rA1) * 2048 + cs1 * 8;
  const u16* srcB0 = Bw + (size_t)(bn * 128 + rA0) * 2048 + cs0 * 8;
  const u16* srcB1 = Bw + (size_t)(bn * 128 + rA1) * 2048 + cs1 * 8;
  char* dstA0 = (char*)As + (w * 2 + 0) * 1024;
  char* dstA1 = (char*)As + (w * 2 + 1) * 1024;
  char* dstB0 = (char*)Bs + (w * 2 + 0) * 1024;
  char* dstB1 = (char*)Bs + (w * 2 + 1) * 1024;

  for (int kt = 0; kt < 64; ++kt) {
    __syncthreads();
    gll16(dstA0, srcA0 + kt * 32);
    gll16(dstA1, srcA1 + kt * 32);
    gll16(dstB0, srcB0 + kt * 32);
    gll16(dstB1, srcB1 + kt * 32);
    __syncthreads();
    short8 af[4], bfr[4];
#pragma unroll
    for (int mi = 0; mi < 4; ++mi) {
      int row = wr * 64 + mi * 16 + li;
      int ch = lg ^ (row & 3);
      af[mi] = *(const short8*)((const char*)As + row * 64 + ch * 16);
    }
#pragma unroll
    for (int ni = 0; ni < 4; ++ni) {
      int row = wc * 64 + ni * 16 + li;
      int ch = lg ^ (row & 3);
      bfr[ni] = *(const short8*)((const char*)Bs + row * 64 + ch * 16);
    }
#pragma unroll
    for (int mi = 0; mi < 4; ++mi)
#pragma unroll
      for (int ni = 0; ni < 4; ++ni)
        acc[mi][ni] = MFMA16(af[mi], bfr[ni], acc[mi][ni]);
  }
#pragma unroll
  for (int mi = 0; mi < 4; ++mi)
#pragma unroll
    for (int ni = 0; ni < 4; ++ni) {
      int n = bn * 128 + wc * 64 + ni * 16 + li;
#pragma unroll
      for (int r = 0; r < 4; ++r) {
        int m = bm * 128 + wr * 64 + mi * 16 + lg * 4 + r;
        C[(size_t)m * 2048 + n] = f2bf(acc[mi][ni][r]);
      }
    }
}

// ---- RMSNorm + RoPE (+ log-pos scale for Q) in fp32, out hi/lo bf16 ----
__global__ __launch_bounds__(256)
void qk_process_kernel(const float* __restrict__ Qf, const float* __restrict__ Kf,
                       const float* __restrict__ cosT, const float* __restrict__ sinT,
                       const float* __restrict__ scaler,
                       u16* __restrict__ Qph, u16* __restrict__ Qpl,
                       u16* __restrict__ Kph, u16* __restrict__ Kpl) {
  const int r = blockIdx.x * 4 + (threadIdx.x >> 6);
  const int l = threadIdx.x & 63;
  const bool isQ = (blockIdx.y == 0);
  const float* src = isQ ? Qf : Kf;
  u16* dsth = isQ ? Qph : Kph;
  u16* dstl = isQ ? Qpl : Kpl;
  const int b = r >> 15;
  const int t = (r >> 4) & 2047;
  const int h = r & 15;
  float v1 = src[(size_t)r * 128 + l];
  float v2 = src[(size_t)r * 128 + l + 64];
  float ss = v1 * v1 + v2 * v2;
#pragma unroll
  for (int off = 1; off < 64; off <<= 1) ss += __shfl_xor(ss, off);
  float rr = rsqrtf(ss * (1.f / 128.f) + 1.1920929e-07f);
  float c = cosT[t * 64 + l], s = sinT[t * 64 + l];
  float n1 = v1 * rr, n2 = v2 * rr;
  float o1 = n1 * c + n2 * s;
  float o2 = n2 * c - n1 * s;
  if (isQ) {
    float mlt = scaler[h] * logf((float)(t + 1));
    o1 *= mlt; o2 *= mlt;
  }
  size_t orow = ((size_t)(b * 16 + h) * 2048 + t) * 128;
  u16 h1 = f2bf(o1), h2 = f2bf(o2);
  dsth[orow + l] = h1;
  dsth[orow + l + 64] = h2;
  dstl[orow + l] = f2bf(o1 - bf2f(h1));
  dstl[orow + l + 64] = f2bf(o2 - bf2f(h2));
}

// ---------------- V: [b][t][hv*256+dv] bf16 -> Vt [b*8+hv][dv][t] ----------------
__global__ __launch_bounds__(256)
void v_transpose_kernel(const u16* __restrict__ Vg, u16* __restrict__ Vt) {
  __shared__ u16 tile[32][34];
  const int bz = blockIdx.z;           // b*8+hv
  const int b = bz >> 3, hv = bz & 7;
  const int t0 = blockIdx.x * 32, dv0 = blockIdx.y * 32;
  const int tx = threadIdx.x & 31, ty = threadIdx.x >> 5;
#pragma unroll
  for (int s = 0; s < 4; ++s) {
    int t = t0 + ty + s * 8;
    tile[ty + s * 8][tx] = Vg[(size_t)(b * 2048 + t) * 2048 + hv * 256 + dv0 + tx];
  }
  __syncthreads();
#pragma unroll
  for (int s = 0; s < 4; ++s) {
    int dv = dv0 + ty + s * 8;
    Vt[((size_t)bz * 256 + dv) * 2048 + t0 + tx] = tile[tx][ty + s * 8];
  }
}

// ---------------- causal flash attention (split-bf16 QK^T) ----------------
// 2-phase double-buffered pipeline (T3 minimum recipe):
//   STAGE(next) -> vmcnt(8) -> s_barrier -> compute(cur) -> s_barrier
// Prefetch loads stay in flight across barriers (never drain to 0 mid-loop).
// grid: 1024 blocks, XCD-chunked swizzle so one bh's 32 qt-blocks share an L2.
__global__ __launch_bounds__(256, 2)
void attn_kernel(const u16* __restrict__ Qph, const u16* __restrict__ Qpl,
                 const u16* __restrict__ Kph, const u16* __restrict__ Kpl,
                 const u16* __restrict__ Vt,
                 float* __restrict__ Y1, float* __restrict__ Y2) {
  __shared__ u16 Ksh[2][KBLK * 128];  // [key][feat] hi, chunk^(key&7) swizzle
  __shared__ u16 Ksl[2][KBLK * 128];  // lo plane
  __shared__ u16 Vs[2][256 * KBLK];   // [dv][key],  chunk^((dv>>1)&3) swizzle
  __shared__ u16 Ps[4][16 * 56];      // per-wave P [qrow][key], stride 56 u16

  // XCD-chunked block swizzle: XCD x hosts lids [x*128, (x+1)*128) = 4 bh groups
  const int lid = ((blockIdx.x & 7) << 7) | (blockIdx.x >> 3);
  const int qt = lid & 31;
  const int bh = lid >> 5;
  const int b = bh >> 4, h = bh & 15;
  const int grp = h >> 3, hv = h & 7;
  const u16* QhP = Qph + (size_t)bh * (T_ * HD_);
  const u16* QlP = Qpl + (size_t)bh * (T_ * HD_);
  const u16* KhP = Kph + (size_t)bh * (T_ * HD_);
  const u16* KlP = Kpl + (size_t)bh * (T_ * HD_);
  const u16* Vh = Vt + (size_t)(b * 8 + hv) * (256 * T_);
  float* Yout = (grp ? Y2 : Y1) + ((size_t)(b * 8 + hv) * T_ + qt * QBLK) * 256;

  const int tid = threadIdx.x;
  const int w = tid >> 6, l = tid & 63;
  const int li = l & 15, lg = l >> 4;
  const int q0 = qt * QBLK + w * 16;

  // staging geometry (per wave: 4 K-chunk loads + 4 V-chunk loads = 8 gll16)
  int kRow[2], kCs[2], vDv[4], vCs[4];
#pragma unroll
  for (int i = 0; i < 2; ++i) {
    int o = (w * 2 + i) * 1024 + l * 16;
    kRow[i] = o >> 8;
    kCs[i] = ((o >> 4) & 15) ^ (kRow[i] & 7);
  }
#pragma unroll
  for (int i = 0; i < 4; ++i) {
    int o = (w * 4 + i) * 1024 + l * 16;
    vDv[i] = o >> 6;
    vCs[i] = ((o >> 4) & 3) ^ ((vDv[i] >> 1) & 3);
  }

#define STAGE(bi, kv0)                                                          \
  do {                                                                          \
    _Pragma("unroll")                                                           \
    for (int i = 0; i < 2; ++i) {                                               \
      gll16((char*)Ksh[bi] + (w * 2 + i) * 1024,                                \
            KhP + (size_t)((kv0) + kRow[i]) * 128 + kCs[i] * 8);                \
      gll16((char*)Ksl[bi] + (w * 2 + i) * 1024,                                \
            KlP + (size_t)((kv0) + kRow[i]) * 128 + kCs[i] * 8);                \
    }                                                                           \
    _Pragma("unroll")                                                           \
    for (int i = 0; i < 4; ++i)                                                 \
      gll16((char*)Vs[bi] + (w * 4 + i) * 1024,                                 \
            Vh + (size_t)vDv[i] * T_ + (kv0) + vCs[i] * 8);                     \
  } while (0)

  // prologue: stage buffer 0, then pull Q into registers
  STAGE(0, 0);

  short8 qfh[4], qfl[4];
  {
    const u16* qrowh = QhP + (size_t)(q0 + li) * 128;
    const u16* qrowl = QlP + (size_t)(q0 + li) * 128;
#pragma unroll
    for (int kc = 0; kc < 4; ++kc) {
      qfh[kc] = *(const short8*)(qrowh + kc * 32 + lg * 8);
      qfl[kc] = *(const short8*)(qrowl + kc * 32 + lg * 8);
    }
  }
  f32x4 acc[16] = {};
  float m[4], se[4];
#pragma unroll
  for (int r = 0; r < 4; ++r) { m[r] = -1e30f; se[r] = 0.f; }

  const int nkv = (qt + 1) * QBLK / KBLK;
  for (int kv = 0; kv < nkv; ++kv) {
    const int kv0 = kv * KBLK;
    const int cur = kv & 1;
    if (kv + 1 < nkv) {
      STAGE(cur ^ 1, kv0 + KBLK);
      asm volatile("s_waitcnt vmcnt(8)" ::: "memory");
    } else {
      asm volatile("s_waitcnt vmcnt(0)" ::: "memory");
    }
    __builtin_amdgcn_s_barrier();
    if (kv0 <= q0 + 15) {
      f32x4 s0 = {}, s1 = {};
      __builtin_amdgcn_s_setprio(1);
#pragma unroll
      for (int kc = 0; kc < 4; ++kc) {
        int ch = kc * 4 + lg;
        int off0 = li * 256 + ((ch ^ (li & 7)) * 16);
        int off1 = (li + 16) * 256 + ((ch ^ (li & 7)) * 16);
        const short8 k0h = *(const short8*)((const char*)Ksh[cur] + off0);
        const short8 k1h = *(const short8*)((const char*)Ksh[cur] + off1);
        const short8 k0l = *(const short8*)((const char*)Ksl[cur] + off0);
        const short8 k1l = *(const short8*)((const char*)Ksl[cur] + off1);
        s0 = MFMA16(qfh[kc], k0h, s0);
        s0 = MFMA16(qfh[kc], k0l, s0);
        s0 = MFMA16(qfl[kc], k0h, s0);
        s1 = MFMA16(qfh[kc], k1h, s1);
        s1 = MFMA16(qfh[kc], k1l, s1);
        s1 = MFMA16(qfl[kc], k1h, s1);
      }
      __builtin_amdgcn_s_setprio(0);
      const float scale = 0.08838834764831845f;  // 1/sqrt(128)
      float corr[4];
#pragma unroll
      for (int r = 0; r < 4; ++r) {
        const int qr = q0 + lg * 4 + r;
        float v0 = s0[r] * scale, v1 = s1[r] * scale;
        if (kv0 + li > qr) v0 = -1e30f;
        if (kv0 + 16 + li > qr) v1 = -1e30f;
        float tmx = fmaxf(v0, v1);
        tmx = fmaxf(tmx, __shfl_xor(tmx, 1));
        tmx = fmaxf(tmx, __shfl_xor(tmx, 2));
        tmx = fmaxf(tmx, __shfl_xor(tmx, 4));
        tmx = fmaxf(tmx, __shfl_xor(tmx, 8));
        const float mn = fmaxf(m[r], tmx);
        corr[r] = exp2f((m[r] - mn) * 1.4426950408889634f);
        float p0 = exp2f((v0 - mn) * 1.4426950408889634f);
        float p1 = exp2f((v1 - mn) * 1.4426950408889634f);
        m[r] = mn;
        float rs = p0 + p1;
        rs += __shfl_xor(rs, 1);
        rs += __shfl_xor(rs, 2);
        rs += __shfl_xor(rs, 4);
        rs += __shfl_xor(rs, 8);
        se[r] = se[r] * corr[r] + rs;
        s0[r] = p0; s1[r] = p1;
      }
#pragma unroll
      for (int nt = 0; nt < 16; ++nt) {
        f32x4 a = acc[nt];
        a[0] *= corr[0]; a[1] *= corr[1]; a[2] *= corr[2]; a[3] *= corr[3];
        acc[nt] = a;
      }
      u16* Pw = &Ps[w][0];
#pragma unroll
      for (int r = 0; r < 4; ++r) {
        Pw[(lg * 4 + r) * 56 + li] = f2bf(s0[r]);
        Pw[(lg * 4 + r) * 56 + 16 + li] = f2bf(s1[r]);
      }
      const short8 pa = *(const short8*)((const char*)Pw + li * 112 + lg * 16);
      __builtin_amdgcn_s_setprio(1);
#pragma unroll
      for (int nt = 0; nt < 16; ++nt) {
        const int dv = nt * 16 + li;
        const int ch = lg ^ ((dv >> 1) & 3);
        const short8 vf = *(const short8*)((const char*)Vs[cur] + dv * 64 + ch * 16);
        acc[nt] = MFMA16(pa, vf, acc[nt]);
      }
      __builtin_amdgcn_s_setprio(0);
    }
    __builtin_amdgcn_s_barrier();  // no vmcnt drain: prefetch stays in flight
  }
  float inv[4];
#pragma unroll
  for (int r = 0; r < 4; ++r) inv[r] = 1.0f / se[r];
#pragma unroll
  for (int nt = 0; nt < 16; ++nt)
#pragma unroll
    for (int r = 0; r < 4; ++r)
      Yout[(size_t)(w * 16 + lg * 4 + r) * 256 + nt * 16 + li] = acc[nt][r] * inv[r];
#undef STAGE
}

// ---------------- combine: y = y1 - lambda*y2, layout back ----------------
__global__ __launch_bounds__(256)
void combine_kernel(const float* __restrict__ Y1, const float* __restrict__ Y2,
                    const float* __restrict__ lamp, float* __restrict__ out) {
  size_t f = ((size_t)blockIdx.x * 256 + threadIdx.x) * 4;
  int dv = (int)(f & 255);
  int hv = (int)((f >> 8) & 7);
  size_t bt = f >> 11;
  int t = (int)(bt & 2047);
  int b = (int)(bt >> 11);
  const float lam = lamp[0];
  size_t yi = ((size_t)(b * 8 + hv) * 2048 + t) * 256 + dv;
  float4 a = *(const float4*)(Y1 + yi);
  float4 c = *(const float4*)(Y2 + yi);
  float4 o;
  o.x = a.x - lam * c.x; o.y = a.y - lam * c.y;
  o.z = a.z - lam * c.z; o.w = a.w - lam * c.w;
  *(float4*)(out + f) = o;
}

// ---------------- launch ----------------
extern "C" void kernel_launch(void* const* d_in, const int* in_sizes, int n_in,
                              void* d_out, int out_size, void* d_ws, size_t ws_size,
                              hipStream_t stream) {
  const float* x   = (const float*)d_in[0];
  const float* Wq  = (const float*)d_in[1];
  const float* Wk  = (const float*)d_in[2];
  const float* Wv  = (const float*)d_in[3];
  const float* lq1 = (const float*)d_in[4];
  const float* lk1 = (const float*)d_in[5];
  const float* lq2 = (const float*)d_in[6];
  const float* lk2 = (const float*)d_in[7];
  const float* scl = (const float*)d_in[8];
  float* out = (float*)d_out;

  char* ws = (char*)d_ws;
  // phase-1 buffers
  u16*  Xh   = (u16*)(ws + 0);            // 16 MB  (later aliased by Qph)
  u16*  Xl   = (u16*)(ws + 16777216);     // 16 MB  (later aliased by Qpl)
  u16*  Wqh  = (u16*)(ws + 33554432);     // 8 MB   (later aliased by Kph)
  u16*  Wql  = (u16*)(ws + 41943040);     // 8 MB
  u16*  Wkh  = (u16*)(ws + 50331648);     // 8 MB   (later aliased by Kpl)
  u16*  Wkl  = (u16*)(ws + 58720256);     // 8 MB
  u16*  Wvh  = (u16*)(ws + 67108864);     // 8 MB
  float* Qf  = (float*)(ws + 75497472);   // 32 MB  (later aliased by Y1)
  float* Kf  = (float*)(ws + 109051904);  // 32 MB  (later aliased by Y2)
  u16*  Vg   = (u16*)(ws + 142606336);    // 16 MB
  u16*  Vt   = (u16*)(ws + 159383552);    // 16 MB
  float* cosT = (float*)(ws + 176160768); // 0.5 MB
  float* sinT = (float*)(ws + 176685056); // 0.5 MB
  float* lam  = (float*)(ws + 177209344); // 4 B
  // phase-2 aliases (dead-buffer reuse; same-stream ordering makes this safe)
  u16*  Qph = (u16*)(ws + 0);
  u16*  Qpl = (u16*)(ws + 16777216);
  u16*  Kph = (u16*)(ws + 33554432);
  u16*  Kpl = (u16*)(ws + 50331648);
  float* Y1 = (float*)(ws + 75497472);
  float* Y2 = (float*)(ws + 109051904);

  cast_split_x_kernel<<<8192, 256, 0, stream>>>(x, Xh, Xl);
  wt_split_kernel<<<dim3(64, 64, 3), 256, 0, stream>>>(Wq, Wk, Wv, Wqh, Wql, Wkh, Wkl, Wvh);
  rope_table_kernel<<<2048, 64, 0, stream>>>(cosT, sinT);
  lambda_kernel<<<1, 64, 0, stream>>>(lq1, lk1, lq2, lk2, lam);
  gemm_split_kernel<<<dim3(16, 32, 2), 256, 0, stream>>>(Xh, Xl, Wqh, Wql, Wkh, Wkl, Qf, Kf);
  gemm_v_kernel<<<dim3(16, 32), 256, 0, stream>>>(Xh, Wvh, Vg);
  qk_process_kernel<<<dim3(16384, 2), 256, 0, stream>>>(Qf, Kf, cosT, sinT, scl, Qph, Qpl, Kph, Kpl);
  v_transpose_kernel<<<dim3(64, 8, 16), 256, 0, stream>>>(Vg, Vt);
  attn_kernel<<<1024, 256, 0, stream>>>(Qph, Qpl, Kph, Kpl, Vt, Y1, Y2);
  combine_kernel<<<8192, 256, 0, stream>>>(Y1, Y2, lam, out);
}

// Round 4
// 527.589 us; speedup vs baseline: 1.3190x; 1.1799x over previous
//
#include <hip/hip_runtime.h>

typedef unsigned short u16;
typedef __attribute__((ext_vector_type(8))) short short8;
typedef __attribute__((ext_vector_type(4))) float f32x4;
typedef __attribute__((ext_vector_type(4))) unsigned short u16x4;

#define B_  2
#define T_  2048
#define D_  2048
#define NH_ 16
#define HD_ 128
#define QBLK 64
#define KBLK 32

#define MFMA16(a,b,c) __builtin_amdgcn_mfma_f32_16x16x32_bf16((a),(b),(c),0,0,0)

__device__ __forceinline__ float bf2f(u16 h) {
  union { unsigned int u; float f; } v; v.u = ((unsigned int)h) << 16; return v.f;
}
__device__ __forceinline__ u16 f2bf(float f) {
  union { float f; unsigned int u; } v; v.f = f;
  unsigned int r = v.u + 0x7FFFu + ((v.u >> 16) & 1u);
  return (u16)(r >> 16);
}

// global -> LDS direct copy, 16B per lane. dst must be wave-uniform.
__device__ __forceinline__ void gll16(void* lds, const void* g) {
  __builtin_amdgcn_global_load_lds(
      (const __attribute__((address_space(1))) unsigned int*)(size_t)(g),
      (__attribute__((address_space(3))) unsigned int*)(unsigned int)(size_t)(lds),
      16, 0, 0);
}

// ---------------- x fp32 -> bf16 hi + lo residual planes ----------------
__global__ __launch_bounds__(256)
void cast_split_x_kernel(const float* __restrict__ X, u16* __restrict__ Xh,
                         u16* __restrict__ Xl) {
  size_t i = ((size_t)blockIdx.x * 256 + threadIdx.x) * 4;
  float4 v = *(const float4*)(X + i);
  u16x4 h, l;
  h.x = f2bf(v.x); l.x = f2bf(v.x - bf2f(h.x));
  h.y = f2bf(v.y); l.y = f2bf(v.y - bf2f(h.y));
  h.z = f2bf(v.z); l.z = f2bf(v.z - bf2f(h.z));
  h.w = f2bf(v.w); l.w = f2bf(v.w - bf2f(h.w));
  *(u16x4*)(Xh + i) = h;
  *(u16x4*)(Xl + i) = l;
}

// -------- W fp32 [k][n] -> bf16 Wt [n][k], hi(+lo for q,k) planes --------
__global__ __launch_bounds__(256)
void wt_split_kernel(const float* __restrict__ Wq, const float* __restrict__ Wk,
                     const float* __restrict__ Wv,
                     u16* __restrict__ Wqh, u16* __restrict__ Wql,
                     u16* __restrict__ Wkh, u16* __restrict__ Wkl,
                     u16* __restrict__ Wvh) {
  __shared__ float tile[32][33];
  const int z = blockIdx.z;
  const float* W = z == 0 ? Wq : (z == 1 ? Wk : Wv);
  u16* Oh = z == 0 ? Wqh : (z == 1 ? Wkh : Wvh);
  u16* Ol = z == 0 ? Wql : Wkl;  // unused for z==2
  int k0 = blockIdx.x * 32, n0 = blockIdx.y * 32;
  int tx = threadIdx.x & 31, ty = threadIdx.x >> 5;
#pragma unroll
  for (int s = 0; s < 4; ++s)
    tile[ty + s * 8][tx] = W[(size_t)(k0 + ty + s * 8) * 2048 + n0 + tx];
  __syncthreads();
#pragma unroll
  for (int s = 0; s < 4; ++s) {
    float w = tile[tx][ty + s * 8];
    u16 h = f2bf(w);
    size_t o = (size_t)(n0 + ty + s * 8) * 2048 + k0 + tx;
    Oh[o] = h;
    if (z < 2) Ol[o] = f2bf(w - bf2f(h));
  }
}

// ---------------- RoPE table: cos/sin [T][64] fp32 ----------------
__global__ void rope_table_kernel(float* __restrict__ cosT, float* __restrict__ sinT) {
  int t = blockIdx.x, d = threadIdx.x;  // 64 threads
  float invf = exp2f(-(float)d * (13.287712379549449f / 64.f));  // 10000^(-d/64)
  float fr = (float)t * invf;
  cosT[t * 64 + d] = cosf(fr);
  sinT[t * 64 + d] = sinf(fr);
}

// ---------------- lambda scalar ----------------
__global__ void lambda_kernel(const float* __restrict__ lq1, const float* __restrict__ lk1,
                              const float* __restrict__ lq2, const float* __restrict__ lk2,
                              float* __restrict__ lam) {
  int l = threadIdx.x;  // 64
  float a = lq1[l] * lk1[l];
  float b = lq2[l] * lk2[l];
#pragma unroll
  for (int off = 1; off < 64; off <<= 1) { a += __shfl_xor(a, off); b += __shfl_xor(b, off); }
  if (l == 0) lam[0] = expf(a) - expf(b) + 0.2f;
}

// ------ split GEMM: C = (Xh+Xl)(4096x2048) * (Wh+Wl)^T -> fp32 (q,k) ------
// 3-term: hh + hl + lh. 128x128 tile, 4 waves 2x2, BK=32.
// grid (512, 2): XCD-chunked bn-major swizzle -> B panel L2-resident per XCD.
__global__ __launch_bounds__(256)
void gemm_split_kernel(const u16* __restrict__ Ah, const u16* __restrict__ Al,
                       const u16* __restrict__ Wqh, const u16* __restrict__ Wql,
                       const u16* __restrict__ Wkh, const u16* __restrict__ Wkl,
                       float* __restrict__ Qf, float* __restrict__ Kf) {
  __shared__ u16 Ash[128 * 32];
  __shared__ u16 Asl[128 * 32];
  __shared__ u16 Bsh[128 * 32];
  __shared__ u16 Bsl[128 * 32];
  const int bid = blockIdx.x, z = blockIdx.y;
  const int lid = ((bid & 7) << 6) | (bid >> 3);
  const int bn = lid >> 5, bm = lid & 31;
  const u16* Bh = z ? Wkh : Wqh;
  const u16* Bl = z ? Wkl : Wql;
  float* C = z ? Kf : Qf;
  const int tid = threadIdx.x;
  const int w = tid >> 6, l = tid & 63;
  const int li = l & 15, lg = l >> 4;
  const int wr = w >> 1, wc = w & 1;

  f32x4 acc[4][4] = {};

  int rowc[2], csc[2];
#pragma unroll
  for (int i = 0; i < 2; ++i) {
    int o = (w * 2 + i) * 1024 + l * 16;
    rowc[i] = o >> 6;
    csc[i] = ((o >> 4) & 3) ^ (rowc[i] & 3);
  }
  const u16* sAh[2]; const u16* sAl[2]; const u16* sBh[2]; const u16* sBl[2];
  char* dA[2]; char* dAl2[2]; char* dB[2]; char* dBl2[2];
#pragma unroll
  for (int i = 0; i < 2; ++i) {
    size_t ao = (size_t)(bm * 128 + rowc[i]) * 2048 + csc[i] * 8;
    size_t bo = (size_t)(bn * 128 + rowc[i]) * 2048 + csc[i] * 8;
    sAh[i] = Ah + ao; sAl[i] = Al + ao;
    sBh[i] = Bh + bo; sBl[i] = Bl + bo;
    dA[i]   = (char*)Ash + (w * 2 + i) * 1024;
    dAl2[i] = (char*)Asl + (w * 2 + i) * 1024;
    dB[i]   = (char*)Bsh + (w * 2 + i) * 1024;
    dBl2[i] = (char*)Bsl + (w * 2 + i) * 1024;
  }

  for (int kt = 0; kt < 64; ++kt) {
    __syncthreads();
#pragma unroll
    for (int i = 0; i < 2; ++i) {
      gll16(dA[i],   sAh[i] + kt * 32);
      gll16(dAl2[i], sAl[i] + kt * 32);
      gll16(dB[i],   sBh[i] + kt * 32);
      gll16(dBl2[i], sBl[i] + kt * 32);
    }
    __syncthreads();
    short8 ah[4], al[4], bh[4], bl[4];
#pragma unroll
    for (int mi = 0; mi < 4; ++mi) {
      int row = wr * 64 + mi * 16 + li;
      int ch = lg ^ (row & 3);
      ah[mi] = *(const short8*)((const char*)Ash + row * 64 + ch * 16);
      al[mi] = *(const short8*)((const char*)Asl + row * 64 + ch * 16);
    }
#pragma unroll
    for (int ni = 0; ni < 4; ++ni) {
      int row = wc * 64 + ni * 16 + li;
      int ch = lg ^ (row & 3);
      bh[ni] = *(const short8*)((const char*)Bsh + row * 64 + ch * 16);
      bl[ni] = *(const short8*)((const char*)Bsl + row * 64 + ch * 16);
    }
#pragma unroll
    for (int mi = 0; mi < 4; ++mi)
#pragma unroll
      for (int ni = 0; ni < 4; ++ni) {
        acc[mi][ni] = MFMA16(ah[mi], bh[ni], acc[mi][ni]);
        acc[mi][ni] = MFMA16(ah[mi], bl[ni], acc[mi][ni]);
        acc[mi][ni] = MFMA16(al[mi], bh[ni], acc[mi][ni]);
      }
  }
#pragma unroll
  for (int mi = 0; mi < 4; ++mi)
#pragma unroll
    for (int ni = 0; ni < 4; ++ni) {
      int n = bn * 128 + wc * 64 + ni * 16 + li;
#pragma unroll
      for (int r = 0; r < 4; ++r) {
        int m = bm * 128 + wr * 64 + mi * 16 + lg * 4 + r;
        C[(size_t)m * 2048 + n] = acc[mi][ni][r];
      }
    }
}

// ------------- plain GEMM for V: Xh * Wvh^T -> bf16 -------------
__global__ __launch_bounds__(256)
void gemm_v_kernel(const u16* __restrict__ Xb, const u16* __restrict__ Bw,
                   u16* __restrict__ C) {
  __shared__ u16 As[128 * 32];
  __shared__ u16 Bs[128 * 32];
  const int bid = blockIdx.x;
  const int lid = ((bid & 7) << 6) | (bid >> 3);
  const int bn = lid >> 5, bm = lid & 31;
  const int tid = threadIdx.x;
  const int w = tid >> 6, l = tid & 63;
  const int li = l & 15, lg = l >> 4;
  const int wr = w >> 1, wc = w & 1;

  f32x4 acc[4][4] = {};

  const int o0 = (w * 2 + 0) * 1024 + l * 16;
  const int o1 = (w * 2 + 1) * 1024 + l * 16;
  const int rA0 = o0 >> 6, rA1 = o1 >> 6;
  const int cs0 = ((o0 >> 4) & 3) ^ (rA0 & 3);
  const int cs1 = ((o1 >> 4) & 3) ^ (rA1 & 3);
  const u16* srcA0 = Xb + (size_t)(bm * 128 + rA0) * 2048 + cs0 * 8;
  const u16* srcA1 = Xb + (size_t)(bm * 128 + rA1) * 2048 + cs1 * 8;
  const u16* srcB0 = Bw + (size_t)(bn * 128 + rA0) * 2048 + cs0 * 8;
  const u16* srcB1 = Bw + (size_t)(bn * 128 + rA1) * 2048 + cs1 * 8;
  char* dstA0 = (char*)As + (w * 2 + 0) * 1024;
  char* dstA1 = (char*)As + (w * 2 + 1) * 1024;
  char* dstB0 = (char*)Bs + (w * 2 + 0) * 1024;
  char* dstB1 = (char*)Bs + (w * 2 + 1) * 1024;

  for (int kt = 0; kt < 64; ++kt) {
    __syncthreads();
    gll16(dstA0, srcA0 + kt * 32);
    gll16(dstA1, srcA1 + kt * 32);
    gll16(dstB0, srcB0 + kt * 32);
    gll16(dstB1, srcB1 + kt * 32);
    __syncthreads();
    short8 af[4], bfr[4];
#pragma unroll
    for (int mi = 0; mi < 4; ++mi) {
      int row = wr * 64 + mi * 16 + li;
      int ch = lg ^ (row & 3);
      af[mi] = *(const short8*)((const char*)As + row * 64 + ch * 16);
    }
#pragma unroll
    for (int ni = 0; ni < 4; ++ni) {
      int row = wc * 64 + ni * 16 + li;
      int ch = lg ^ (row & 3);
      bfr[ni] = *(const short8*)((const char*)Bs + row * 64 + ch * 16);
    }
#pragma unroll
    for (int mi = 0; mi < 4; ++mi)
#pragma unroll
      for (int ni = 0; ni < 4; ++ni)
        acc[mi][ni] = MFMA16(af[mi], bfr[ni], acc[mi][ni]);
  }
#pragma unroll
  for (int mi = 0; mi < 4; ++mi)
#pragma unroll
    for (int ni = 0; ni < 4; ++ni) {
      int n = bn * 128 + wc * 64 + ni * 16 + li;
#pragma unroll
      for (int r = 0; r < 4; ++r) {
        int m = bm * 128 + wr * 64 + mi * 16 + lg * 4 + r;
        C[(size_t)m * 2048 + n] = f2bf(acc[mi][ni][r]);
      }
    }
}

// ---- RMSNorm + RoPE (+ log-pos*scaler*1/sqrt(HD) for Q), out hi/lo bf16 ----
__global__ __launch_bounds__(256)
void qk_process_kernel(const float* __restrict__ Qf, const float* __restrict__ Kf,
                       const float* __restrict__ cosT, const float* __restrict__ sinT,
                       const float* __restrict__ scaler,
                       u16* __restrict__ Qph, u16* __restrict__ Qpl,
                       u16* __restrict__ Kph, u16* __restrict__ Kpl) {
  const int r = blockIdx.x * 4 + (threadIdx.x >> 6);
  const int l = threadIdx.x & 63;
  const bool isQ = (blockIdx.y == 0);
  const float* src = isQ ? Qf : Kf;
  u16* dsth = isQ ? Qph : Kph;
  u16* dstl = isQ ? Qpl : Kpl;
  const int b = r >> 15;
  const int t = (r >> 4) & 2047;
  const int h = r & 15;
  float v1 = src[(size_t)r * 128 + l];
  float v2 = src[(size_t)r * 128 + l + 64];
  float ss = v1 * v1 + v2 * v2;
#pragma unroll
  for (int off = 1; off < 64; off <<= 1) ss += __shfl_xor(ss, off);
  float rr = rsqrtf(ss * (1.f / 128.f) + 1.1920929e-07f);
  float c = cosT[t * 64 + l], s = sinT[t * 64 + l];
  float n1 = v1 * rr, n2 = v2 * rr;
  float o1 = n1 * c + n2 * s;
  float o2 = n2 * c - n1 * s;
  if (isQ) {
    // fold softmax scale 1/sqrt(128) into Q
    float mlt = scaler[h] * logf((float)(t + 1)) * 0.08838834764831845f;
    o1 *= mlt; o2 *= mlt;
  }
  size_t orow = ((size_t)(b * 16 + h) * 2048 + t) * 128;
  u16 h1 = f2bf(o1), h2 = f2bf(o2);
  dsth[orow + l] = h1;
  dsth[orow + l + 64] = h2;
  dstl[orow + l] = f2bf(o1 - bf2f(h1));
  dstl[orow + l + 64] = f2bf(o2 - bf2f(h2));
}

// ---------------- V: [b][t][hv*256+dv] bf16 -> Vt [b*8+hv][dv][t] ----------------
__global__ __launch_bounds__(256)
void v_transpose_kernel(const u16* __restrict__ Vg, u16* __restrict__ Vt) {
  __shared__ u16 tile[32][34];
  const int bz = blockIdx.z;           // b*8+hv
  const int b = bz >> 3, hv = bz & 7;
  const int t0 = blockIdx.x * 32, dv0 = blockIdx.y * 32;
  const int tx = threadIdx.x & 31, ty = threadIdx.x >> 5;
#pragma unroll
  for (int s = 0; s < 4; ++s) {
    int t = t0 + ty + s * 8;
    tile[ty + s * 8][tx] = Vg[(size_t)(b * 2048 + t) * 2048 + hv * 256 + dv0 + tx];
  }
  __syncthreads();
#pragma unroll
  for (int s = 0; s < 4; ++s) {
    int dv = dv0 + ty + s * 8;
    Vt[((size_t)bz * 256 + dv) * 2048 + t0 + tx] = tile[tx][ty + s * 8];
  }
}

// ---------------- causal flash attention (split-bf16 QK^T) ----------------
// Balanced pairing: block handles q-tiles (31-pr) then (pr) -> 66 kv-steps/block.
// 512 blocks = exactly 2/CU resident, no straggler tail.
// 2-phase dbuf: STAGE(next); vmcnt(8); s_barrier; compute; s_barrier.
__global__ __launch_bounds__(256, 2)
void attn_kernel(const u16* __restrict__ Qph, const u16* __restrict__ Qpl,
                 const u16* __restrict__ Kph, const u16* __restrict__ Kpl,
                 const u16* __restrict__ Vt,
                 float* __restrict__ Y1, float* __restrict__ Y2) {
  __shared__ u16 Ksh[2][KBLK * 128];  // [key][feat] hi, chunk^(key&7) swizzle
  __shared__ u16 Ksl[2][KBLK * 128];  // lo plane
  __shared__ u16 Vs[2][256 * KBLK];   // [dv][key],  chunk^((dv>>1)&3) swizzle
  __shared__ u16 Ps[4][16 * 32];      // per-wave P [row][slot^((row>>1)&3)][key&7]

  const int bid = blockIdx.x;
  const int lid = ((bid & 7) << 6) | (bid >> 3);  // 512 blocks, XCD-chunked
  const int pr = lid & 15;                        // pair index 0..15
  const int bh = lid >> 4;
  const int b = bh >> 4, h = bh & 15;
  const int grp = h >> 3, hv = h & 7;
  const u16* QhP = Qph + (size_t)bh * (T_ * HD_);
  const u16* QlP = Qpl + (size_t)bh * (T_ * HD_);
  const u16* KhP = Kph + (size_t)bh * (T_ * HD_);
  const u16* KlP = Kpl + (size_t)bh * (T_ * HD_);
  const u16* Vh = Vt + (size_t)(b * 8 + hv) * (256 * T_);
  float* Ybase = (grp ? Y2 : Y1) + (size_t)(b * 8 + hv) * T_ * 256;

  const int tid = threadIdx.x;
  const int w = tid >> 6, l = tid & 63;
  const int li = l & 15, lg = l >> 4;

  // staging geometry (per wave: 4 K-chunk loads + 4 V-chunk loads = 8 gll16)
  int kRow[2], kCs[2], vDv[4], vCs[4];
#pragma unroll
  for (int i = 0; i < 2; ++i) {
    int o = (w * 2 + i) * 1024 + l * 16;
    kRow[i] = o >> 8;
    kCs[i] = ((o >> 4) & 15) ^ (kRow[i] & 7);
  }
#pragma unroll
  for (int i = 0; i < 4; ++i) {
    int o = (w * 4 + i) * 1024 + l * 16;
    vDv[i] = o >> 6;
    vCs[i] = ((o >> 4) & 3) ^ ((vDv[i] >> 1) & 3);
  }

#define STAGE(bi, kv0)                                                          \
  do {                                                                          \
    _Pragma("unroll")                                                           \
    for (int i = 0; i < 2; ++i) {                                               \
      gll16((char*)Ksh[bi] + (w * 2 + i) * 1024,                                \
            KhP + (size_t)((kv0) + kRow[i]) * 128 + kCs[i] * 8);                \
      gll16((char*)Ksl[bi] + (w * 2 + i) * 1024,                                \
            KlP + (size_t)((kv0) + kRow[i]) * 128 + kCs[i] * 8);                \
    }                                                                           \
    _Pragma("unroll")                                                           \
    for (int i = 0; i < 4; ++i)                                                 \
      gll16((char*)Vs[bi] + (w * 4 + i) * 1024,                                 \
            Vh + (size_t)vDv[i] * T_ + (kv0) + vCs[i] * 8);                     \
  } while (0)

  const float L2E = 1.4426950408889634f;

#pragma unroll 1
  for (int t2 = 0; t2 < 2; ++t2) {
    const int qt = t2 ? pr : 31 - pr;
    const int q0 = qt * QBLK + w * 16;

    STAGE(0, 0);

    short8 qfh[4], qfl[4];
    {
      const u16* qrowh = QhP + (size_t)(q0 + li) * 128;
      const u16* qrowl = QlP + (size_t)(q0 + li) * 128;
#pragma unroll
      for (int kc = 0; kc < 4; ++kc) {
        qfh[kc] = *(const short8*)(qrowh + kc * 32 + lg * 8);
        qfl[kc] = *(const short8*)(qrowl + kc * 32 + lg * 8);
      }
    }
    f32x4 acc[16] = {};
    float m[4], se[4];
#pragma unroll
    for (int r = 0; r < 4; ++r) { m[r] = -1e30f; se[r] = 0.f; }

    const int nkv = (qt + 1) * 2;
    for (int kv = 0; kv < nkv; ++kv) {
      const int kv0 = kv * KBLK;
      const int cur = kv & 1;
      if (kv + 1 < nkv) {
        STAGE(cur ^ 1, kv0 + KBLK);
        asm volatile("s_waitcnt vmcnt(8)" ::: "memory");
      } else {
        asm volatile("s_waitcnt vmcnt(0)" ::: "memory");
      }
      __builtin_amdgcn_s_barrier();
      if (kv0 <= q0 + 15) {
        f32x4 s0 = {}, s1 = {}, s0b = {}, s1b = {};
        __builtin_amdgcn_s_setprio(1);
#pragma unroll
        for (int kc = 0; kc < 2; ++kc) {
          int ch = kc * 4 + lg;
          int off0 = li * 256 + ((ch ^ (li & 7)) * 16);
          int off1 = (li + 16) * 256 + ((ch ^ (li & 7)) * 16);
          const short8 k0h = *(const short8*)((const char*)Ksh[cur] + off0);
          const short8 k1h = *(const short8*)((const char*)Ksh[cur] + off1);
          const short8 k0l = *(const short8*)((const char*)Ksl[cur] + off0);
          const short8 k1l = *(const short8*)((const char*)Ksl[cur] + off1);
          s0 = MFMA16(qfh[kc], k0h, s0);
          s0 = MFMA16(qfh[kc], k0l, s0);
          s0 = MFMA16(qfl[kc], k0h, s0);
          s1 = MFMA16(qfh[kc], k1h, s1);
          s1 = MFMA16(qfh[kc], k1l, s1);
          s1 = MFMA16(qfl[kc], k1h, s1);
        }
#pragma unroll
        for (int kc = 2; kc < 4; ++kc) {
          int ch = kc * 4 + lg;
          int off0 = li * 256 + ((ch ^ (li & 7)) * 16);
          int off1 = (li + 16) * 256 + ((ch ^ (li & 7)) * 16);
          const short8 k0h = *(const short8*)((const char*)Ksh[cur] + off0);
          const short8 k1h = *(const short8*)((const char*)Ksh[cur] + off1);
          const short8 k0l = *(const short8*)((const char*)Ksl[cur] + off0);
          const short8 k1l = *(const short8*)((const char*)Ksl[cur] + off1);
          s0b = MFMA16(qfh[kc], k0h, s0b);
          s0b = MFMA16(qfh[kc], k0l, s0b);
          s0b = MFMA16(qfl[kc], k0h, s0b);
          s1b = MFMA16(qfh[kc], k1h, s1b);
          s1b = MFMA16(qfh[kc], k1l, s1b);
          s1b = MFMA16(qfl[kc], k1h, s1b);
        }
        __builtin_amdgcn_s_setprio(0);
        s0 += s0b; s1 += s1b;

        // masking (skip when the whole 32-key tile is below all rows)
        float v0[4], v1[4], tmx[4];
        const bool nomask = (kv0 + 31 <= q0);
#pragma unroll
        for (int r = 0; r < 4; ++r) {
          float a = s0[r], bb = s1[r];
          if (!nomask) {
            const int qr = q0 + lg * 4 + r;
            if (kv0 + li > qr) a = -1e30f;
            if (kv0 + 16 + li > qr) bb = -1e30f;
          }
          float t = fmaxf(a, bb);
          t = fmaxf(t, __shfl_xor(t, 1));
          t = fmaxf(t, __shfl_xor(t, 2));
          t = fmaxf(t, __shfl_xor(t, 4));
          t = fmaxf(t, __shfl_xor(t, 8));
          v0[r] = a; v1[r] = bb; tmx[r] = t;
        }
        // defer-rescale (T13): only rescale when max grew past threshold
        int need = (tmx[0] > m[0] + 8.f) | (tmx[1] > m[1] + 8.f) |
                   (tmx[2] > m[2] + 8.f) | (tmx[3] > m[3] + 8.f);
        if (__any(need)) {
          float corr[4];
#pragma unroll
          for (int r = 0; r < 4; ++r) {
            float mn = fmaxf(m[r], tmx[r]);
            corr[r] = exp2f((m[r] - mn) * L2E);
            m[r] = mn;
            se[r] *= corr[r];
          }
#pragma unroll
          for (int nt = 0; nt < 16; ++nt) {
            f32x4 a = acc[nt];
            a[0] *= corr[0]; a[1] *= corr[1]; a[2] *= corr[2]; a[3] *= corr[3];
            acc[nt] = a;
          }
        }
        u16* Pw = &Ps[w][0];
#pragma unroll
        for (int r = 0; r < 4; ++r) {
          float p0 = exp2f((v0[r] - m[r]) * L2E);
          float p1 = exp2f((v1[r] - m[r]) * L2E);
          float rs = p0 + p1;
          rs += __shfl_xor(rs, 1);
          rs += __shfl_xor(rs, 2);
          rs += __shfl_xor(rs, 4);
          rs += __shfl_xor(rs, 8);
          se[r] += rs;
          const int rowA = lg * 4 + r;
          const int x = (rowA >> 1) & 3;
          Pw[rowA * 32 + (((li >> 3) ^ x) * 8) + (li & 7)] = f2bf(p0);
          Pw[rowA * 32 + ((((li >> 3) | 2) ^ x) * 8) + (li & 7)] = f2bf(p1);
        }
        const short8 pa = *(const short8*)(Pw + li * 32 + ((lg ^ ((li >> 1) & 3)) * 8));
        __builtin_amdgcn_s_setprio(1);
#pragma unroll
        for (int nt = 0; nt < 16; ++nt) {
          const int dv = nt * 16 + li;
          const int ch = lg ^ ((dv >> 1) & 3);
          const short8 vf = *(const short8*)((const char*)Vs[cur] + dv * 64 + ch * 16);
          acc[nt] = MFMA16(pa, vf, acc[nt]);
        }
        __builtin_amdgcn_s_setprio(0);
      }
      __builtin_amdgcn_s_barrier();  // no vmcnt drain: prefetch stays in flight
    }
    float inv[4];
#pragma unroll
    for (int r = 0; r < 4; ++r) inv[r] = 1.0f / se[r];
    float* Yout = Ybase + (size_t)(qt * QBLK) * 256;
#pragma unroll
    for (int nt = 0; nt < 16; ++nt)
#pragma unroll
      for (int r = 0; r < 4; ++r)
        Yout[(size_t)(w * 16 + lg * 4 + r) * 256 + nt * 16 + li] = acc[nt][r] * inv[r];
  }
#undef STAGE
}

// ---------------- combine: y = y1 - lambda*y2, layout back ----------------
__global__ __launch_bounds__(256)
void combine_kernel(const float* __restrict__ Y1, const float* __restrict__ Y2,
                    const float* __restrict__ lamp, float* __restrict__ out) {
  size_t f = ((size_t)blockIdx.x * 256 + threadIdx.x) * 4;
  int dv = (int)(f & 255);
  int hv = (int)((f >> 8) & 7);
  size_t bt = f >> 11;
  int t = (int)(bt & 2047);
  int b = (int)(bt >> 11);
  const float lam = lamp[0];
  size_t yi = ((size_t)(b * 8 + hv) * 2048 + t) * 256 + dv;
  float4 a = *(const float4*)(Y1 + yi);
  float4 c = *(const float4*)(Y2 + yi);
  float4 o;
  o.x = a.x - lam * c.x; o.y = a.y - lam * c.y;
  o.z = a.z - lam * c.z; o.w = a.w - lam * c.w;
  *(float4*)(out + f) = o;
}

// ---------------- launch ----------------
extern "C" void kernel_launch(void* const* d_in, const int* in_sizes, int n_in,
                              void* d_out, int out_size, void* d_ws, size_t ws_size,
                              hipStream_t stream) {
  const float* x   = (const float*)d_in[0];
  const float* Wq  = (const float*)d_in[1];
  const float* Wk  = (const float*)d_in[2];
  const float* Wv  = (const float*)d_in[3];
  const float* lq1 = (const float*)d_in[4];
  const float* lk1 = (const float*)d_in[5];
  const float* lq2 = (const float*)d_in[6];
  const float* lk2 = (const float*)d_in[7];
  const float* scl = (const float*)d_in[8];
  float* out = (float*)d_out;

  char* ws = (char*)d_ws;
  // phase-1 buffers
  u16*  Xh   = (u16*)(ws + 0);            // 16 MB  (later aliased by Qph)
  u16*  Xl   = (u16*)(ws + 16777216);     // 16 MB  (later aliased by Qpl)
  u16*  Wqh  = (u16*)(ws + 33554432);     // 8 MB   (later aliased by Kph)
  u16*  Wql  = (u16*)(ws + 41943040);     // 8 MB
  u16*  Wkh  = (u16*)(ws + 50331648);     // 8 MB   (later aliased by Kpl)
  u16*  Wkl  = (u16*)(ws + 58720256);     // 8 MB
  u16*  Wvh  = (u16*)(ws + 67108864);     // 8 MB
  float* Qf  = (float*)(ws + 75497472);   // 32 MB  (later aliased by Y1)
  float* Kf  = (float*)(ws + 109051904);  // 32 MB  (later aliased by Y2)
  u16*  Vg   = (u16*)(ws + 142606336);    // 16 MB
  u16*  Vt   = (u16*)(ws + 159383552);    // 16 MB
  float* cosT = (float*)(ws + 176160768); // 0.5 MB
  float* sinT = (float*)(ws + 176685056); // 0.5 MB
  float* lam  = (float*)(ws + 177209344); // 4 B
  // phase-2 aliases (dead-buffer reuse; same-stream ordering makes this safe)
  u16*  Qph = (u16*)(ws + 0);
  u16*  Qpl = (u16*)(ws + 16777216);
  u16*  Kph = (u16*)(ws + 33554432);
  u16*  Kpl = (u16*)(ws + 50331648);
  float* Y1 = (float*)(ws + 75497472);
  float* Y2 = (float*)(ws + 109051904);

  cast_split_x_kernel<<<8192, 256, 0, stream>>>(x, Xh, Xl);
  wt_split_kernel<<<dim3(64, 64, 3), 256, 0, stream>>>(Wq, Wk, Wv, Wqh, Wql, Wkh, Wkl, Wvh);
  rope_table_kernel<<<2048, 64, 0, stream>>>(cosT, sinT);
  lambda_kernel<<<1, 64, 0, stream>>>(lq1, lk1, lq2, lk2, lam);
  gemm_split_kernel<<<dim3(512, 2), 256, 0, stream>>>(Xh, Xl, Wqh, Wql, Wkh, Wkl, Qf, Kf);
  gemm_v_kernel<<<512, 256, 0, stream>>>(Xh, Wvh, Vg);
  qk_process_kernel<<<dim3(16384, 2), 256, 0, stream>>>(Qf, Kf, cosT, sinT, scl, Qph, Qpl, Kph, Kpl);
  v_transpose_kernel<<<dim3(64, 8, 16), 256, 0, stream>>>(Vg, Vt);
  attn_kernel<<<512, 256, 0, stream>>>(Qph, Qpl, Kph, Kpl, Vt, Y1, Y2);
  combine_kernel<<<8192, 256, 0, stream>>>(Y1, Y2, lam, out);
}

// Round 5
// 377.426 us; speedup vs baseline: 1.8438x; 1.3979x over previous
//
#include <hip/hip_runtime.h>

typedef unsigned short u16;
typedef _Float16 f16;
typedef __attribute__((ext_vector_type(8))) _Float16 half8;
typedef __attribute__((ext_vector_type(4))) _Float16 half4;
typedef __attribute__((ext_vector_type(4))) float f32x4;

#define B_  2
#define T_  2048
#define D_  2048
#define NH_ 16
#define HD_ 128
#define QBLK 64
#define KBLK 32

#define MFMAH(a,b,c) __builtin_amdgcn_mfma_f32_16x16x32_f16((a),(b),(c),0,0,0)

// global -> LDS direct copy, 16B per lane. dst must be wave-uniform.
__device__ __forceinline__ void gll16(void* lds, const void* g) {
  __builtin_amdgcn_global_load_lds(
      (const __attribute__((address_space(1))) unsigned int*)(size_t)(g),
      (__attribute__((address_space(3))) unsigned int*)(unsigned int)(size_t)(lds),
      16, 0, 0);
}

// ---------------- x fp32 -> fp16 ----------------
__global__ __launch_bounds__(256)
void cast_x_kernel(const float* __restrict__ X, f16* __restrict__ Xb) {
  size_t i = ((size_t)blockIdx.x * 256 + threadIdx.x) * 4;
  float4 v = *(const float4*)(X + i);
  half4 o;
  o.x = (f16)v.x; o.y = (f16)v.y; o.z = (f16)v.z; o.w = (f16)v.w;
  *(half4*)(Xb + i) = o;
}

// -------- W fp32 [k][n] -> fp16 Wt [z][n][k] (cast + transpose) --------
__global__ __launch_bounds__(256)
void wt_kernel(const float* __restrict__ Wq, const float* __restrict__ Wk,
               const float* __restrict__ Wv, f16* __restrict__ Wt) {
  __shared__ float tile[32][33];
  const int z = blockIdx.z;
  const float* W = z == 0 ? Wq : (z == 1 ? Wk : Wv);
  f16* O = Wt + (size_t)z * (2048 * 2048);
  int k0 = blockIdx.x * 32, n0 = blockIdx.y * 32;
  int tx = threadIdx.x & 31, ty = threadIdx.x >> 5;
#pragma unroll
  for (int s = 0; s < 4; ++s)
    tile[ty + s * 8][tx] = W[(size_t)(k0 + ty + s * 8) * 2048 + n0 + tx];
  __syncthreads();
#pragma unroll
  for (int s = 0; s < 4; ++s)
    O[(size_t)(n0 + ty + s * 8) * 2048 + k0 + tx] = (f16)tile[tx][ty + s * 8];
}

// ---------------- RoPE table: cos/sin [T][64] fp32 ----------------
__global__ void rope_table_kernel(float* __restrict__ cosT, float* __restrict__ sinT) {
  int t = blockIdx.x, d = threadIdx.x;  // 64 threads
  float invf = exp2f(-(float)d * (13.287712379549449f / 64.f));  // 10000^(-d/64)
  float fr = (float)t * invf;
  cosT[t * 64 + d] = cosf(fr);
  sinT[t * 64 + d] = sinf(fr);
}

// ---------------- lambda scalar ----------------
__global__ void lambda_kernel(const float* __restrict__ lq1, const float* __restrict__ lk1,
                              const float* __restrict__ lq2, const float* __restrict__ lk2,
                              float* __restrict__ lam) {
  int l = threadIdx.x;  // 64
  float a = lq1[l] * lk1[l];
  float b = lq2[l] * lk2[l];
#pragma unroll
  for (int off = 1; off < 64; off <<= 1) { a += __shfl_xor(a, off); b += __shfl_xor(b, off); }
  if (l == 0) lam[0] = expf(a) - expf(b) + 0.2f;
}

// ---- fp16 GEMM: C[z] = Xb(4096x2048) * Wt[z]^T; z<2 -> fp32, z==2 -> fp16 ----
// 128x128 tile, 4 waves 2x2, BK=32. XCD-chunked bn-major swizzle.
__global__ __launch_bounds__(256)
void gemm_qkv_kernel(const f16* __restrict__ Xb, const f16* __restrict__ Wt,
                     float* __restrict__ Qf, float* __restrict__ Kf,
                     f16* __restrict__ Vg) {
  __shared__ f16 As[128 * 32];
  __shared__ f16 Bs[128 * 32];
  const int bid = blockIdx.x, z = blockIdx.y;
  const int lid = ((bid & 7) << 6) | (bid >> 3);
  const int bn = lid >> 5, bm = lid & 31;
  const f16* Bw = Wt + (size_t)z * (2048 * 2048);
  const int tid = threadIdx.x;
  const int w = tid >> 6, l = tid & 63;
  const int li = l & 15, lg = l >> 4;
  const int wr = w >> 1, wc = w & 1;

  f32x4 acc[4][4] = {};

  const int o0 = (w * 2 + 0) * 1024 + l * 16;
  const int o1 = (w * 2 + 1) * 1024 + l * 16;
  const int rA0 = o0 >> 6, rA1 = o1 >> 6;
  const int cs0 = ((o0 >> 4) & 3) ^ (rA0 & 3);
  const int cs1 = ((o1 >> 4) & 3) ^ (rA1 & 3);
  const f16* srcA0 = Xb + (size_t)(bm * 128 + rA0) * 2048 + cs0 * 8;
  const f16* srcA1 = Xb + (size_t)(bm * 128 + rA1) * 2048 + cs1 * 8;
  const f16* srcB0 = Bw + (size_t)(bn * 128 + rA0) * 2048 + cs0 * 8;
  const f16* srcB1 = Bw + (size_t)(bn * 128 + rA1) * 2048 + cs1 * 8;
  char* dstA0 = (char*)As + (w * 2 + 0) * 1024;
  char* dstA1 = (char*)As + (w * 2 + 1) * 1024;
  char* dstB0 = (char*)Bs + (w * 2 + 0) * 1024;
  char* dstB1 = (char*)Bs + (w * 2 + 1) * 1024;

  for (int kt = 0; kt < 64; ++kt) {
    __syncthreads();
    gll16(dstA0, srcA0 + kt * 32);
    gll16(dstA1, srcA1 + kt * 32);
    gll16(dstB0, srcB0 + kt * 32);
    gll16(dstB1, srcB1 + kt * 32);
    __syncthreads();
    half8 af[4], bfr[4];
#pragma unroll
    for (int mi = 0; mi < 4; ++mi) {
      int row = wr * 64 + mi * 16 + li;
      int ch = lg ^ (row & 3);
      af[mi] = *(const half8*)((const char*)As + row * 64 + ch * 16);
    }
#pragma unroll
    for (int ni = 0; ni < 4; ++ni) {
      int row = wc * 64 + ni * 16 + li;
      int ch = lg ^ (row & 3);
      bfr[ni] = *(const half8*)((const char*)Bs + row * 64 + ch * 16);
    }
#pragma unroll
    for (int mi = 0; mi < 4; ++mi)
#pragma unroll
      for (int ni = 0; ni < 4; ++ni)
        acc[mi][ni] = MFMAH(af[mi], bfr[ni], acc[mi][ni]);
  }
  if (z < 2) {
    float* C = z ? Kf : Qf;
#pragma unroll
    for (int mi = 0; mi < 4; ++mi)
#pragma unroll
      for (int ni = 0; ni < 4; ++ni) {
        int n = bn * 128 + wc * 64 + ni * 16 + li;
#pragma unroll
        for (int r = 0; r < 4; ++r) {
          int m = bm * 128 + wr * 64 + mi * 16 + lg * 4 + r;
          C[(size_t)m * 2048 + n] = acc[mi][ni][r];
        }
      }
  } else {
#pragma unroll
    for (int mi = 0; mi < 4; ++mi)
#pragma unroll
      for (int ni = 0; ni < 4; ++ni) {
        int n = bn * 128 + wc * 64 + ni * 16 + li;
#pragma unroll
        for (int r = 0; r < 4; ++r) {
          int m = bm * 128 + wr * 64 + mi * 16 + lg * 4 + r;
          Vg[(size_t)m * 2048 + n] = (f16)acc[mi][ni][r];
        }
      }
  }
}

// ---- RMSNorm + RoPE (+ log-pos*scaler*1/sqrt(HD) for Q), fp32 -> fp16 ----
__global__ __launch_bounds__(256)
void qk_process_kernel(const float* __restrict__ Qf, const float* __restrict__ Kf,
                       const float* __restrict__ cosT, const float* __restrict__ sinT,
                       const float* __restrict__ scaler,
                       f16* __restrict__ Qp, f16* __restrict__ Kp) {
  const int r = blockIdx.x * 4 + (threadIdx.x >> 6);
  const int l = threadIdx.x & 63;
  const bool isQ = (blockIdx.y == 0);
  const float* src = isQ ? Qf : Kf;
  f16* dst = isQ ? Qp : Kp;
  const int b = r >> 15;
  const int t = (r >> 4) & 2047;
  const int h = r & 15;
  float v1 = src[(size_t)r * 128 + l];
  float v2 = src[(size_t)r * 128 + l + 64];
  float ss = v1 * v1 + v2 * v2;
#pragma unroll
  for (int off = 1; off < 64; off <<= 1) ss += __shfl_xor(ss, off);
  float rr = rsqrtf(ss * (1.f / 128.f) + 1.1920929e-07f);
  float c = cosT[t * 64 + l], s = sinT[t * 64 + l];
  float n1 = v1 * rr, n2 = v2 * rr;
  float o1 = n1 * c + n2 * s;
  float o2 = n2 * c - n1 * s;
  if (isQ) {
    // fold softmax scale 1/sqrt(128) into Q
    float mlt = scaler[h] * logf((float)(t + 1)) * 0.08838834764831845f;
    o1 *= mlt; o2 *= mlt;
  }
  size_t orow = ((size_t)(b * 16 + h) * 2048 + t) * 128;
  dst[orow + l] = (f16)o1;
  dst[orow + l + 64] = (f16)o2;
}

// ------------- V: [b][t][hv*256+dv] fp16 -> Vt [b*8+hv][dv][t] -------------
__global__ __launch_bounds__(256)
void v_transpose_kernel(const f16* __restrict__ Vg, f16* __restrict__ Vt) {
  __shared__ f16 tile[32][34];
  const int bz = blockIdx.z;           // b*8+hv
  const int b = bz >> 3, hv = bz & 7;
  const int t0 = blockIdx.x * 32, dv0 = blockIdx.y * 32;
  const int tx = threadIdx.x & 31, ty = threadIdx.x >> 5;
#pragma unroll
  for (int s = 0; s < 4; ++s) {
    int t = t0 + ty + s * 8;
    tile[ty + s * 8][tx] = Vg[(size_t)(b * 2048 + t) * 2048 + hv * 256 + dv0 + tx];
  }
  __syncthreads();
#pragma unroll
  for (int s = 0; s < 4; ++s) {
    int dv = dv0 + ty + s * 8;
    Vt[((size_t)bz * 256 + dv) * 2048 + t0 + tx] = tile[tx][ty + s * 8];
  }
}

// ---------------- causal flash attention (fp16) ----------------
// Balanced pairing: block handles q-tiles (31-pr) then (pr) -> 66 kv-steps.
// 512 blocks, XCD-chunked. 2-phase dbuf: STAGE(next); vmcnt(6); s_barrier;
// compute; s_barrier (no drain mid-loop).
__global__ __launch_bounds__(256, 2)
void attn_kernel(const f16* __restrict__ Qp, const f16* __restrict__ Kp,
                 const f16* __restrict__ Vt,
                 float* __restrict__ Y1, float* __restrict__ Y2) {
  __shared__ f16 Ks[2][KBLK * 128];  // [key][feat], chunk^(key&7) swizzle
  __shared__ f16 Vs[2][256 * KBLK];  // [dv][key],  chunk^((dv>>1)&3) swizzle
  __shared__ f16 Ps[4][16 * 32];     // per-wave P, slot^((row>>1)&3) swizzle

  const int bid = blockIdx.x;
  const int lid = ((bid & 7) << 6) | (bid >> 3);  // 512 blocks, XCD-chunked
  const int pr = lid & 15;                        // pair index 0..15
  const int bh = lid >> 4;
  const int b = bh >> 4, h = bh & 15;
  const int grp = h >> 3, hv = h & 7;
  const f16* QhP = Qp + (size_t)bh * (T_ * HD_);
  const f16* KhP = Kp + (size_t)bh * (T_ * HD_);
  const f16* Vh = Vt + (size_t)(b * 8 + hv) * (256 * T_);
  float* Ybase = (grp ? Y2 : Y1) + (size_t)(b * 8 + hv) * T_ * 256;

  const int tid = threadIdx.x;
  const int w = tid >> 6, l = tid & 63;
  const int li = l & 15, lg = l >> 4;

  // staging geometry (per wave: 2 K-chunk loads + 4 V-chunk loads = 6 gll16)
  int kRow[2], kCs[2], vDv[4], vCs[4];
#pragma unroll
  for (int i = 0; i < 2; ++i) {
    int o = (w * 2 + i) * 1024 + l * 16;
    kRow[i] = o >> 8;
    kCs[i] = ((o >> 4) & 15) ^ (kRow[i] & 7);
  }
#pragma unroll
  for (int i = 0; i < 4; ++i) {
    int o = (w * 4 + i) * 1024 + l * 16;
    vDv[i] = o >> 6;
    vCs[i] = ((o >> 4) & 3) ^ ((vDv[i] >> 1) & 3);
  }

#define STAGE(bi, kv0)                                                          \
  do {                                                                          \
    _Pragma("unroll")                                                           \
    for (int i = 0; i < 2; ++i)                                                 \
      gll16((char*)Ks[bi] + (w * 2 + i) * 1024,                                 \
            KhP + (size_t)((kv0) + kRow[i]) * 128 + kCs[i] * 8);                \
    _Pragma("unroll")                                                           \
    for (int i = 0; i < 4; ++i)                                                 \
      gll16((char*)Vs[bi] + (w * 4 + i) * 1024,                                 \
            Vh + (size_t)vDv[i] * T_ + (kv0) + vCs[i] * 8);                     \
  } while (0)

  const float L2E = 1.4426950408889634f;

#pragma unroll 1
  for (int t2 = 0; t2 < 2; ++t2) {
    const int qt = t2 ? pr : 31 - pr;
    const int q0 = qt * QBLK + w * 16;

    STAGE(0, 0);

    half8 qf[4];
    {
      const f16* qrow = QhP + (size_t)(q0 + li) * 128;
#pragma unroll
      for (int kc = 0; kc < 4; ++kc)
        qf[kc] = *(const half8*)(qrow + kc * 32 + lg * 8);
    }
    f32x4 acc[16] = {};
    float m[4], se[4];
#pragma unroll
    for (int r = 0; r < 4; ++r) { m[r] = -1e30f; se[r] = 0.f; }

    const int nkv = (qt + 1) * 2;
    for (int kv = 0; kv < nkv; ++kv) {
      const int kv0 = kv * KBLK;
      const int cur = kv & 1;
      if (kv + 1 < nkv) {
        STAGE(cur ^ 1, kv0 + KBLK);
        asm volatile("s_waitcnt vmcnt(6)" ::: "memory");
      } else {
        asm volatile("s_waitcnt vmcnt(0)" ::: "memory");
      }
      __builtin_amdgcn_s_barrier();
      if (kv0 <= q0 + 15) {
        f32x4 s0 = {}, s1 = {}, s0b = {}, s1b = {};
        __builtin_amdgcn_s_setprio(1);
#pragma unroll
        for (int kc = 0; kc < 2; ++kc) {
          int ch = kc * 4 + lg;
          int off0 = li * 256 + ((ch ^ (li & 7)) * 16);
          int off1 = (li + 16) * 256 + ((ch ^ (li & 7)) * 16);
          const half8 k0 = *(const half8*)((const char*)Ks[cur] + off0);
          const half8 k1 = *(const half8*)((const char*)Ks[cur] + off1);
          s0 = MFMAH(qf[kc], k0, s0);
          s1 = MFMAH(qf[kc], k1, s1);
        }
#pragma unroll
        for (int kc = 2; kc < 4; ++kc) {
          int ch = kc * 4 + lg;
          int off0 = li * 256 + ((ch ^ (li & 7)) * 16);
          int off1 = (li + 16) * 256 + ((ch ^ (li & 7)) * 16);
          const half8 k0 = *(const half8*)((const char*)Ks[cur] + off0);
          const half8 k1 = *(const half8*)((const char*)Ks[cur] + off1);
          s0b = MFMAH(qf[kc], k0, s0b);
          s1b = MFMAH(qf[kc], k1, s1b);
        }
        __builtin_amdgcn_s_setprio(0);
        s0 += s0b; s1 += s1b;

        // masking (skip when the whole 32-key tile is below all rows)
        float v0[4], v1[4], tmx[4];
        const bool nomask = (kv0 + 31 <= q0);
#pragma unroll
        for (int r = 0; r < 4; ++r) {
          float a = s0[r], bb = s1[r];
          if (!nomask) {
            const int qr = q0 + lg * 4 + r;
            if (kv0 + li > qr) a = -1e30f;
            if (kv0 + 16 + li > qr) bb = -1e30f;
          }
          float t = fmaxf(a, bb);
          t = fmaxf(t, __shfl_xor(t, 1));
          t = fmaxf(t, __shfl_xor(t, 2));
          t = fmaxf(t, __shfl_xor(t, 4));
          t = fmaxf(t, __shfl_xor(t, 8));
          v0[r] = a; v1[r] = bb; tmx[r] = t;
        }
        // defer-rescale (T13): only rescale when max grew past threshold
        int need = (tmx[0] > m[0] + 8.f) | (tmx[1] > m[1] + 8.f) |
                   (tmx[2] > m[2] + 8.f) | (tmx[3] > m[3] + 8.f);
        if (__any(need)) {
          float corr[4];
#pragma unroll
          for (int r = 0; r < 4; ++r) {
            float mn = fmaxf(m[r], tmx[r]);
            corr[r] = exp2f((m[r] - mn) * L2E);
            m[r] = mn;
            se[r] *= corr[r];
          }
#pragma unroll
          for (int nt = 0; nt < 16; ++nt) {
            f32x4 a = acc[nt];
            a[0] *= corr[0]; a[1] *= corr[1]; a[2] *= corr[2]; a[3] *= corr[3];
            acc[nt] = a;
          }
        }
        f16* Pw = &Ps[w][0];
#pragma unroll
        for (int r = 0; r < 4; ++r) {
          float p0 = exp2f((v0[r] - m[r]) * L2E);
          float p1 = exp2f((v1[r] - m[r]) * L2E);
          float rs = p0 + p1;
          rs += __shfl_xor(rs, 1);
          rs += __shfl_xor(rs, 2);
          rs += __shfl_xor(rs, 4);
          rs += __shfl_xor(rs, 8);
          se[r] += rs;
          const int rowA = lg * 4 + r;
          const int x = (rowA >> 1) & 3;
          Pw[rowA * 32 + (((li >> 3) ^ x) * 8) + (li & 7)] = (f16)p0;
          Pw[rowA * 32 + ((((li >> 3) | 2) ^ x) * 8) + (li & 7)] = (f16)p1;
        }
        const half8 pa = *(const half8*)(Pw + li * 32 + ((lg ^ ((li >> 1) & 3)) * 8));
        __builtin_amdgcn_s_setprio(1);
#pragma unroll
        for (int nt = 0; nt < 16; ++nt) {
          const int dv = nt * 16 + li;
          const int ch = lg ^ ((dv >> 1) & 3);
          const half8 vf = *(const half8*)((const char*)Vs[cur] + dv * 64 + ch * 16);
          acc[nt] = MFMAH(pa, vf, acc[nt]);
        }
        __builtin_amdgcn_s_setprio(0);
      }
      __builtin_amdgcn_s_barrier();  // no vmcnt drain: prefetch stays in flight
    }
    float inv[4];
#pragma unroll
    for (int r = 0; r < 4; ++r) inv[r] = 1.0f / se[r];
    float* Yout = Ybase + (size_t)(qt * QBLK) * 256;
#pragma unroll
    for (int nt = 0; nt < 16; ++nt)
#pragma unroll
      for (int r = 0; r < 4; ++r)
        Yout[(size_t)(w * 16 + lg * 4 + r) * 256 + nt * 16 + li] = acc[nt][r] * inv[r];
  }
#undef STAGE
}

// ---------------- combine: y = y1 - lambda*y2, layout back ----------------
__global__ __launch_bounds__(256)
void combine_kernel(const float* __restrict__ Y1, const float* __restrict__ Y2,
                    const float* __restrict__ lamp, float* __restrict__ out) {
  size_t f = ((size_t)blockIdx.x * 256 + threadIdx.x) * 4;
  int dv = (int)(f & 255);
  int hv = (int)((f >> 8) & 7);
  size_t bt = f >> 11;
  int t = (int)(bt & 2047);
  int b = (int)(bt >> 11);
  const float lam = lamp[0];
  size_t yi = ((size_t)(b * 8 + hv) * 2048 + t) * 256 + dv;
  float4 a = *(const float4*)(Y1 + yi);
  float4 c = *(const float4*)(Y2 + yi);
  float4 o;
  o.x = a.x - lam * c.x; o.y = a.y - lam * c.y;
  o.z = a.z - lam * c.z; o.w = a.w - lam * c.w;
  *(float4*)(out + f) = o;
}

// ---------------- launch ----------------
extern "C" void kernel_launch(void* const* d_in, const int* in_sizes, int n_in,
                              void* d_out, int out_size, void* d_ws, size_t ws_size,
                              hipStream_t stream) {
  const float* x   = (const float*)d_in[0];
  const float* Wq  = (const float*)d_in[1];
  const float* Wk  = (const float*)d_in[2];
  const float* Wv  = (const float*)d_in[3];
  const float* lq1 = (const float*)d_in[4];
  const float* lk1 = (const float*)d_in[5];
  const float* lq2 = (const float*)d_in[6];
  const float* lk2 = (const float*)d_in[7];
  const float* scl = (const float*)d_in[8];
  float* out = (float*)d_out;

  char* ws = (char*)d_ws;
  f16*  Xb  = (f16*)(ws + 0);             // 16.78 MB (aliased by Qp later)
  f16*  Wt  = (f16*)(ws + 16777216);      // 25.17 MB (aliased by Kp later)
  float* Qf = (float*)(ws + 41943040);    // 33.55 MB (aliased by Y1)
  float* Kf = (float*)(ws + 75497472);    // 33.55 MB (aliased by Y2)
  f16*  Vg  = (f16*)(ws + 109051904);     // 16.78 MB
  f16*  Vt  = (f16*)(ws + 125829120);     // 16.78 MB
  float* cosT = (float*)(ws + 142606336); // 0.5 MB
  float* sinT = (float*)(ws + 143130624); // 0.5 MB
  float* lam  = (float*)(ws + 143654912); // 4 B
  // phase-2 aliases (dead-buffer reuse; same-stream ordering makes this safe)
  f16*  Qp = (f16*)(ws + 0);
  f16*  Kp = (f16*)(ws + 16777216);
  float* Y1 = (float*)(ws + 41943040);
  float* Y2 = (float*)(ws + 75497472);

  cast_x_kernel<<<8192, 256, 0, stream>>>(x, Xb);
  wt_kernel<<<dim3(64, 64, 3), 256, 0, stream>>>(Wq, Wk, Wv, Wt);
  rope_table_kernel<<<2048, 64, 0, stream>>>(cosT, sinT);
  lambda_kernel<<<1, 64, 0, stream>>>(lq1, lk1, lq2, lk2, lam);
  gemm_qkv_kernel<<<dim3(512, 3), 256, 0, stream>>>(Xb, Wt, Qf, Kf, Vg);
  qk_process_kernel<<<dim3(16384, 2), 256, 0, stream>>>(Qf, Kf, cosT, sinT, scl, Qp, Kp);
  v_transpose_kernel<<<dim3(64, 8, 16), 256, 0, stream>>>(Vg, Vt);
  attn_kernel<<<512, 256, 0, stream>>>(Qp, Kp, Vt, Y1, Y2);
  combine_kernel<<<8192, 256, 0, stream>>>(Y1, Y2, lam, out);
}

// Round 6
// 347.106 us; speedup vs baseline: 2.0049x; 1.0874x over previous
//
#include <hip/hip_runtime.h>

typedef unsigned short u16;
typedef _Float16 f16;
typedef __attribute__((ext_vector_type(8))) _Float16 half8;
typedef __attribute__((ext_vector_type(4))) _Float16 half4;
typedef __attribute__((ext_vector_type(4))) float f32x4;

#define B_  2
#define T_  2048
#define D_  2048
#define NH_ 16
#define HD_ 128
#define QBLK 64
#define KBLK 32

#define MFMAH(a,b,c) __builtin_amdgcn_mfma_f32_16x16x32_f16((a),(b),(c),0,0,0)

// global -> LDS direct copy, 16B per lane. dst must be wave-uniform.
__device__ __forceinline__ void gll16(void* lds, const void* g) {
  __builtin_amdgcn_global_load_lds(
      (const __attribute__((address_space(1))) unsigned int*)(size_t)(g),
      (__attribute__((address_space(3))) unsigned int*)(unsigned int)(size_t)(lds),
      16, 0, 0);
}

// ---------------- x fp32 -> fp16 ----------------
__global__ __launch_bounds__(256)
void cast_x_kernel(const float* __restrict__ X, f16* __restrict__ Xb) {
  size_t i = ((size_t)blockIdx.x * 256 + threadIdx.x) * 8;
  float4 v0 = *(const float4*)(X + i);
  float4 v1 = *(const float4*)(X + i + 4);
  half8 o;
  o[0] = (f16)v0.x; o[1] = (f16)v0.y; o[2] = (f16)v0.z; o[3] = (f16)v0.w;
  o[4] = (f16)v1.x; o[5] = (f16)v1.y; o[6] = (f16)v1.z; o[7] = (f16)v1.w;
  *(half8*)(Xb + i) = o;
}

// -------- W fp32 [k][n] -> fp16 Wt [z][n'][k]; z<2 rows RoPE-pair-permuted --------
// perm (z<2): head h, dim d -> n' = h*128 + ((d&63)<<1) + (d>>6)
__global__ __launch_bounds__(256)
void wt_kernel(const float* __restrict__ Wq, const float* __restrict__ Wk,
               const float* __restrict__ Wv, f16* __restrict__ Wt) {
  __shared__ float tile[32][33];
  const int z = blockIdx.z;
  const float* W = z == 0 ? Wq : (z == 1 ? Wk : Wv);
  f16* O = Wt + (size_t)z * (2048 * 2048);
  int k0 = blockIdx.x * 32, n0 = blockIdx.y * 32;
  int tx = threadIdx.x & 31, ty = threadIdx.x >> 5;
#pragma unroll
  for (int s = 0; s < 4; ++s)
    tile[ty + s * 8][tx] = W[(size_t)(k0 + ty + s * 8) * 2048 + n0 + tx];
  __syncthreads();
#pragma unroll
  for (int s = 0; s < 4; ++s) {
    int nrow = n0 + ty + s * 8;
    int orow = nrow;
    if (z < 2) {
      int hh = nrow >> 7, dd = nrow & 127;
      orow = (hh << 7) | ((dd & 63) << 1) | (dd >> 6);
    }
    O[(size_t)orow * 2048 + k0 + tx] = (f16)tile[tx][ty + s * 8];
  }
}

// ---------------- RoPE table: cos/sin [T][64] fp32 ----------------
__global__ void rope_table_kernel(float* __restrict__ cosT, float* __restrict__ sinT) {
  int t = blockIdx.x, d = threadIdx.x;  // 64 threads
  float invf = exp2f(-(float)d * (13.287712379549449f / 64.f));  // 10000^(-d/64)
  float fr = (float)t * invf;
  cosT[t * 64 + d] = cosf(fr);
  sinT[t * 64 + d] = sinf(fr);
}

// ---------------- lambda scalar ----------------
__global__ void lambda_kernel(const float* __restrict__ lq1, const float* __restrict__ lk1,
                              const float* __restrict__ lq2, const float* __restrict__ lk2,
                              float* __restrict__ lam) {
  int l = threadIdx.x;  // 64
  float a = lq1[l] * lk1[l];
  float b = lq2[l] * lk2[l];
#pragma unroll
  for (int off = 1; off < 64; off <<= 1) { a += __shfl_xor(a, off); b += __shfl_xor(b, off); }
  if (l == 0) lam[0] = expf(a) - expf(b) + 0.2f;
}

// ---- fp16 GEMM + fused epilogue ----
// z<2: C tile (128 tokens x 1 head, cols RoPE-permuted) -> RMSNorm + RoPE
//      (+ log-pos*scaler*1/sqrt(HD) for Q) -> Qp/Kp fp16 head-major.
// z==2: plain write Vg fp16.
// 128x128 tile, 4 waves 2x2, BK=32, 2-phase dbuf. XCD-chunked swizzle.
__global__ __launch_bounds__(256)
void gemm_qkv_kernel(const f16* __restrict__ Xb, const f16* __restrict__ Wt,
                     const float* __restrict__ cosT, const float* __restrict__ sinT,
                     const float* __restrict__ scaler,
                     f16* __restrict__ Qp, f16* __restrict__ Kp,
                     f16* __restrict__ Vg) {
  __shared__ f16 As[2][128 * 32];
  __shared__ f16 Bs[2][128 * 32];
  __shared__ float ps[4][64];
  const int bid = blockIdx.x, z = blockIdx.y;
  const int lid = ((bid & 7) << 6) | (bid >> 3);
  const int bn = lid >> 5, bm = lid & 31;
  const f16* Bw = Wt + (size_t)z * (2048 * 2048);
  const int tid = threadIdx.x;
  const int w = tid >> 6, l = tid & 63;
  const int li = l & 15, lg = l >> 4;
  const int wr = w >> 1, wc = w & 1;

  f32x4 acc[4][4] = {};

  const int o0 = (w * 2 + 0) * 1024 + l * 16;
  const int o1 = (w * 2 + 1) * 1024 + l * 16;
  const int rA0 = o0 >> 6, rA1 = o1 >> 6;
  const int cs0 = ((o0 >> 4) & 3) ^ (rA0 & 3);
  const int cs1 = ((o1 >> 4) & 3) ^ (rA1 & 3);
  const f16* srcA0 = Xb + (size_t)(bm * 128 + rA0) * 2048 + cs0 * 8;
  const f16* srcA1 = Xb + (size_t)(bm * 128 + rA1) * 2048 + cs1 * 8;
  const f16* srcB0 = Bw + (size_t)(bn * 128 + rA0) * 2048 + cs0 * 8;
  const f16* srcB1 = Bw + (size_t)(bn * 128 + rA1) * 2048 + cs1 * 8;
  const int c0 = (w * 2 + 0) * 1024, c1 = (w * 2 + 1) * 1024;

#define GSTAGE(bi, kt)                                         \
  do {                                                         \
    gll16((char*)As[bi] + c0, srcA0 + (kt) * 32);              \
    gll16((char*)As[bi] + c1, srcA1 + (kt) * 32);              \
    gll16((char*)Bs[bi] + c0, srcB0 + (kt) * 32);              \
    gll16((char*)Bs[bi] + c1, srcB1 + (kt) * 32);              \
  } while (0)

  GSTAGE(0, 0);
  for (int kt = 0; kt < 64; ++kt) {
    const int cur = kt & 1;
    if (kt < 63) {
      GSTAGE(cur ^ 1, kt + 1);
      asm volatile("s_waitcnt vmcnt(4)" ::: "memory");
    } else {
      asm volatile("s_waitcnt vmcnt(0)" ::: "memory");
    }
    __builtin_amdgcn_s_barrier();
    half8 af[4], bfr[4];
#pragma unroll
    for (int mi = 0; mi < 4; ++mi) {
      int row = wr * 64 + mi * 16 + li;
      int ch = lg ^ (row & 3);
      af[mi] = *(const half8*)((const char*)As[cur] + row * 64 + ch * 16);
    }
#pragma unroll
    for (int ni = 0; ni < 4; ++ni) {
      int row = wc * 64 + ni * 16 + li;
      int ch = lg ^ (row & 3);
      bfr[ni] = *(const half8*)((const char*)Bs[cur] + row * 64 + ch * 16);
    }
    __builtin_amdgcn_s_setprio(1);
#pragma unroll
    for (int mi = 0; mi < 4; ++mi)
#pragma unroll
      for (int ni = 0; ni < 4; ++ni)
        acc[mi][ni] = MFMAH(af[mi], bfr[ni], acc[mi][ni]);
    __builtin_amdgcn_s_setprio(0);
    __builtin_amdgcn_s_barrier();
  }
#undef GSTAGE

  if (z == 2) {
#pragma unroll
    for (int mi = 0; mi < 4; ++mi)
#pragma unroll
      for (int ni = 0; ni < 4; ++ni) {
        int n = bn * 128 + wc * 64 + ni * 16 + li;
#pragma unroll
        for (int r = 0; r < 4; ++r) {
          int m = bm * 128 + wr * 64 + mi * 16 + lg * 4 + r;
          Vg[(size_t)m * 2048 + n] = (f16)acc[mi][ni][r];
        }
      }
    return;
  }

  // ---- fused RMSNorm + RoPE epilogue (z<2) ----
  // sum of squares over this wave's 64 cols, per row (mi,lg,r)
  float ss[4][4];
#pragma unroll
  for (int mi = 0; mi < 4; ++mi)
#pragma unroll
    for (int r = 0; r < 4; ++r) {
      float s = acc[mi][0][r] * acc[mi][0][r] + acc[mi][1][r] * acc[mi][1][r] +
                acc[mi][2][r] * acc[mi][2][r] + acc[mi][3][r] * acc[mi][3][r];
      s += __shfl_xor(s, 1);
      s += __shfl_xor(s, 2);
      s += __shfl_xor(s, 4);
      s += __shfl_xor(s, 8);
      ss[mi][r] = s;
    }
  if (li == 0) {
#pragma unroll
    for (int mi = 0; mi < 4; ++mi)
#pragma unroll
      for (int r = 0; r < 4; ++r)
        ps[w][mi * 16 + lg * 4 + r] = ss[mi][r];
  }
  __syncthreads();

  const int h = bn;
  f16* dst = z ? Kp : Qp;
  const float sch = scaler[h] * 0.08838834764831845f;  // scaler * 1/sqrt(128)
#pragma unroll
  for (int mi = 0; mi < 4; ++mi) {
#pragma unroll
    for (int r = 0; r < 4; ++r) {
      const int m = bm * 128 + wr * 64 + mi * 16 + lg * 4 + r;
      const int t = m & 2047, b = m >> 11;
      const int idx = mi * 16 + lg * 4 + r;
      const float tot = ps[wr * 2][idx] + ps[wr * 2 + 1][idx];
      const float rr = rsqrtf(tot * (1.f / 128.f) + 1.1920929e-07f);
      const float lm = z ? 1.f : sch * logf((float)(t + 1));
      f16* drow = dst + ((size_t)(b * 16 + h) * 2048 + t) * 128;
#pragma unroll
      for (int ni = 0; ni < 4; ++ni) {
        const int n = wc * 64 + ni * 16 + li;  // permuted col within head
        const int d1 = n >> 1;
        const float c = cosT[t * 64 + d1], s = sinT[t * 64 + d1];
        float v = acc[mi][ni][r] * rr;
        float vp = __shfl_xor(v, 1);
        float o = (li & 1) ? (v * c - vp * s) : (v * c + vp * s);
        o *= lm;
        drow[d1 + (li & 1) * 64] = (f16)o;
      }
    }
  }
}

// ------------- V: [b][t][hv*256+dv] fp16 -> Vt [b*8+hv][dv][t] -------------
__global__ __launch_bounds__(256)
void v_transpose_kernel(const f16* __restrict__ Vg, f16* __restrict__ Vt) {
  __shared__ f16 tile[32][34];
  const int bz = blockIdx.z;           // b*8+hv
  const int b = bz >> 3, hv = bz & 7;
  const int t0 = blockIdx.x * 32, dv0 = blockIdx.y * 32;
  const int tx = threadIdx.x & 31, ty = threadIdx.x >> 5;
#pragma unroll
  for (int s = 0; s < 4; ++s) {
    int t = t0 + ty + s * 8;
    tile[ty + s * 8][tx] = Vg[(size_t)(b * 2048 + t) * 2048 + hv * 256 + dv0 + tx];
  }
  __syncthreads();
#pragma unroll
  for (int s = 0; s < 4; ++s) {
    int dv = dv0 + ty + s * 8;
    Vt[((size_t)bz * 256 + dv) * 2048 + t0 + tx] = tile[tx][ty + s * 8];
  }
}

// ---------------- causal flash attention (fp16) ----------------
// Balanced pairing: block handles q-tiles (31-pr) then (pr) -> 66 kv-steps.
// 512 blocks, XCD-chunked. 2-phase dbuf. fp16 Y output.
__global__ __launch_bounds__(256, 2)
void attn_kernel(const f16* __restrict__ Qp, const f16* __restrict__ Kp,
                 const f16* __restrict__ Vt,
                 f16* __restrict__ Y1, f16* __restrict__ Y2) {
  __shared__ f16 Ks[2][KBLK * 128];  // [key][feat], chunk^(key&7) swizzle
  __shared__ f16 Vs[2][256 * KBLK];  // [dv][key],  chunk^((dv>>1)&3) swizzle
  __shared__ f16 Ps[4][16 * 32];     // per-wave P, slot^((row>>1)&3) swizzle

  const int bid = blockIdx.x;
  const int lid = ((bid & 7) << 6) | (bid >> 3);  // 512 blocks, XCD-chunked
  const int pr = lid & 15;                        // pair index 0..15
  const int bh = lid >> 4;
  const int b = bh >> 4, h = bh & 15;
  const int grp = h >> 3, hv = h & 7;
  const f16* QhP = Qp + (size_t)bh * (T_ * HD_);
  const f16* KhP = Kp + (size_t)bh * (T_ * HD_);
  const f16* Vh = Vt + (size_t)(b * 8 + hv) * (256 * T_);
  f16* Ybase = (grp ? Y2 : Y1) + (size_t)(b * 8 + hv) * T_ * 256;

  const int tid = threadIdx.x;
  const int w = tid >> 6, l = tid & 63;
  const int li = l & 15, lg = l >> 4;

  // staging geometry (per wave: 2 K-chunk loads + 4 V-chunk loads = 6 gll16)
  int kRow[2], kCs[2], vDv[4], vCs[4];
#pragma unroll
  for (int i = 0; i < 2; ++i) {
    int o = (w * 2 + i) * 1024 + l * 16;
    kRow[i] = o >> 8;
    kCs[i] = ((o >> 4) & 15) ^ (kRow[i] & 7);
  }
#pragma unroll
  for (int i = 0; i < 4; ++i) {
    int o = (w * 4 + i) * 1024 + l * 16;
    vDv[i] = o >> 6;
    vCs[i] = ((o >> 4) & 3) ^ ((vDv[i] >> 1) & 3);
  }

#define STAGE(bi, kv0)                                                          \
  do {                                                                          \
    _Pragma("unroll")                                                           \
    for (int i = 0; i < 2; ++i)                                                 \
      gll16((char*)Ks[bi] + (w * 2 + i) * 1024,                                 \
            KhP + (size_t)((kv0) + kRow[i]) * 128 + kCs[i] * 8);                \
    _Pragma("unroll")                                                           \
    for (int i = 0; i < 4; ++i)                                                 \
      gll16((char*)Vs[bi] + (w * 4 + i) * 1024,                                 \
            Vh + (size_t)vDv[i] * T_ + (kv0) + vCs[i] * 8);                     \
  } while (0)

  const float L2E = 1.4426950408889634f;

#pragma unroll 1
  for (int t2 = 0; t2 < 2; ++t2) {
    const int qt = t2 ? pr : 31 - pr;
    const int q0 = qt * QBLK + w * 16;

    STAGE(0, 0);

    half8 qf[4];
    {
      const f16* qrow = QhP + (size_t)(q0 + li) * 128;
#pragma unroll
      for (int kc = 0; kc < 4; ++kc)
        qf[kc] = *(const half8*)(qrow + kc * 32 + lg * 8);
    }
    f32x4 acc[16] = {};
    float m[4], se[4];
#pragma unroll
    for (int r = 0; r < 4; ++r) { m[r] = -1e30f; se[r] = 0.f; }

    const int nkv = (qt + 1) * 2;
    for (int kv = 0; kv < nkv; ++kv) {
      const int kv0 = kv * KBLK;
      const int cur = kv & 1;
      if (kv + 1 < nkv) {
        STAGE(cur ^ 1, kv0 + KBLK);
        asm volatile("s_waitcnt vmcnt(6)" ::: "memory");
      } else {
        asm volatile("s_waitcnt vmcnt(0)" ::: "memory");
      }
      __builtin_amdgcn_s_barrier();
      if (kv0 <= q0 + 15) {
        f32x4 s0 = {}, s1 = {}, s0b = {}, s1b = {};
        __builtin_amdgcn_s_setprio(1);
#pragma unroll
        for (int kc = 0; kc < 2; ++kc) {
          int ch = kc * 4 + lg;
          int off0 = li * 256 + ((ch ^ (li & 7)) * 16);
          int off1 = (li + 16) * 256 + ((ch ^ (li & 7)) * 16);
          const half8 k0 = *(const half8*)((const char*)Ks[cur] + off0);
          const half8 k1 = *(const half8*)((const char*)Ks[cur] + off1);
          s0 = MFMAH(qf[kc], k0, s0);
          s1 = MFMAH(qf[kc], k1, s1);
        }
#pragma unroll
        for (int kc = 2; kc < 4; ++kc) {
          int ch = kc * 4 + lg;
          int off0 = li * 256 + ((ch ^ (li & 7)) * 16);
          int off1 = (li + 16) * 256 + ((ch ^ (li & 7)) * 16);
          const half8 k0 = *(const half8*)((const char*)Ks[cur] + off0);
          const half8 k1 = *(const half8*)((const char*)Ks[cur] + off1);
          s0b = MFMAH(qf[kc], k0, s0b);
          s1b = MFMAH(qf[kc], k1, s1b);
        }
        __builtin_amdgcn_s_setprio(0);
        s0 += s0b; s1 += s1b;

        // masking (skip when the whole 32-key tile is below all rows)
        float v0[4], v1[4], tmx[4];
        const bool nomask = (kv0 + 31 <= q0);
#pragma unroll
        for (int r = 0; r < 4; ++r) {
          float a = s0[r], bb = s1[r];
          if (!nomask) {
            const int qr = q0 + lg * 4 + r;
            if (kv0 + li > qr) a = -1e30f;
            if (kv0 + 16 + li > qr) bb = -1e30f;
          }
          float t = fmaxf(a, bb);
          t = fmaxf(t, __shfl_xor(t, 1));
          t = fmaxf(t, __shfl_xor(t, 2));
          t = fmaxf(t, __shfl_xor(t, 4));
          t = fmaxf(t, __shfl_xor(t, 8));
          v0[r] = a; v1[r] = bb; tmx[r] = t;
        }
        // defer-rescale (T13): only rescale when max grew past threshold
        int need = (tmx[0] > m[0] + 8.f) | (tmx[1] > m[1] + 8.f) |
                   (tmx[2] > m[2] + 8.f) | (tmx[3] > m[3] + 8.f);
        if (__any(need)) {
          float corr[4];
#pragma unroll
          for (int r = 0; r < 4; ++r) {
            float mn = fmaxf(m[r], tmx[r]);
            corr[r] = exp2f((m[r] - mn) * L2E);
            m[r] = mn;
            se[r] *= corr[r];
          }
#pragma unroll
          for (int nt = 0; nt < 16; ++nt) {
            f32x4 a = acc[nt];
            a[0] *= corr[0]; a[1] *= corr[1]; a[2] *= corr[2]; a[3] *= corr[3];
            acc[nt] = a;
          }
        }
        f16* Pw = &Ps[w][0];
#pragma unroll
        for (int r = 0; r < 4; ++r) {
          float p0 = exp2f((v0[r] - m[r]) * L2E);
          float p1 = exp2f((v1[r] - m[r]) * L2E);
          float rs = p0 + p1;
          rs += __shfl_xor(rs, 1);
          rs += __shfl_xor(rs, 2);
          rs += __shfl_xor(rs, 4);
          rs += __shfl_xor(rs, 8);
          se[r] += rs;
          const int rowA = lg * 4 + r;
          const int x = (rowA >> 1) & 3;
          Pw[rowA * 32 + (((li >> 3) ^ x) * 8) + (li & 7)] = (f16)p0;
          Pw[rowA * 32 + ((((li >> 3) | 2) ^ x) * 8) + (li & 7)] = (f16)p1;
        }
        const half8 pa = *(const half8*)(Pw + li * 32 + ((lg ^ ((li >> 1) & 3)) * 8));
        __builtin_amdgcn_s_setprio(1);
#pragma unroll
        for (int nt = 0; nt < 16; ++nt) {
          const int dv = nt * 16 + li;
          const int ch = lg ^ ((dv >> 1) & 3);
          const half8 vf = *(const half8*)((const char*)Vs[cur] + dv * 64 + ch * 16);
          acc[nt] = MFMAH(pa, vf, acc[nt]);
        }
        __builtin_amdgcn_s_setprio(0);
      }
      __builtin_amdgcn_s_barrier();  // no vmcnt drain: prefetch stays in flight
    }
    float inv[4];
#pragma unroll
    for (int r = 0; r < 4; ++r) inv[r] = 1.0f / se[r];
    f16* Yout = Ybase + (size_t)(qt * QBLK) * 256;
#pragma unroll
    for (int nt = 0; nt < 16; ++nt)
#pragma unroll
      for (int r = 0; r < 4; ++r)
        Yout[(size_t)(w * 16 + lg * 4 + r) * 256 + nt * 16 + li] =
            (f16)(acc[nt][r] * inv[r]);
  }
#undef STAGE
}

// ---------------- combine: y = y1 - lambda*y2 (fp16 in, fp32 out) ----------------
__global__ __launch_bounds__(256)
void combine_kernel(const f16* __restrict__ Y1, const f16* __restrict__ Y2,
                    const float* __restrict__ lamp, float* __restrict__ out) {
  size_t f = ((size_t)blockIdx.x * 256 + threadIdx.x) * 8;
  int dv = (int)(f & 255);
  int hv = (int)((f >> 8) & 7);
  size_t bt = f >> 11;
  int t = (int)(bt & 2047);
  int b = (int)(bt >> 11);
  const float lam = lamp[0];
  size_t yi = ((size_t)(b * 8 + hv) * 2048 + t) * 256 + dv;
  half8 a = *(const half8*)(Y1 + yi);
  half8 c = *(const half8*)(Y2 + yi);
  float4 o0, o1;
  o0.x = (float)a[0] - lam * (float)c[0];
  o0.y = (float)a[1] - lam * (float)c[1];
  o0.z = (float)a[2] - lam * (float)c[2];
  o0.w = (float)a[3] - lam * (float)c[3];
  o1.x = (float)a[4] - lam * (float)c[4];
  o1.y = (float)a[5] - lam * (float)c[5];
  o1.z = (float)a[6] - lam * (float)c[6];
  o1.w = (float)a[7] - lam * (float)c[7];
  *(float4*)(out + f) = o0;
  *(float4*)(out + f + 4) = o1;
}

// ---------------- launch ----------------
extern "C" void kernel_launch(void* const* d_in, const int* in_sizes, int n_in,
                              void* d_out, int out_size, void* d_ws, size_t ws_size,
                              hipStream_t stream) {
  const float* x   = (const float*)d_in[0];
  const float* Wq  = (const float*)d_in[1];
  const float* Wk  = (const float*)d_in[2];
  const float* Wv  = (const float*)d_in[3];
  const float* lq1 = (const float*)d_in[4];
  const float* lk1 = (const float*)d_in[5];
  const float* lq2 = (const float*)d_in[6];
  const float* lk2 = (const float*)d_in[7];
  const float* scl = (const float*)d_in[8];
  float* out = (float*)d_out;

  char* ws = (char*)d_ws;
  f16*  Xb  = (f16*)(ws + 0);             // 16.78 MB
  f16*  Wt  = (f16*)(ws + 16777216);      // 25.17 MB
  f16*  Qp  = (f16*)(ws + 41943040);      // 16.78 MB
  f16*  Kp  = (f16*)(ws + 58720256);      // 16.78 MB
  f16*  Vg  = (f16*)(ws + 75497472);      // 16.78 MB
  f16*  Vt  = (f16*)(ws + 92274688);      // 16.78 MB
  f16*  Y1  = (f16*)(ws + 109051904);     // 16.78 MB
  f16*  Y2  = (f16*)(ws + 125829120);     // 16.78 MB
  float* cosT = (float*)(ws + 142606336); // 0.5 MB
  float* sinT = (float*)(ws + 143130624); // 0.5 MB
  float* lam  = (float*)(ws + 143654912); // 4 B

  cast_x_kernel<<<4096, 256, 0, stream>>>(x, Xb);
  wt_kernel<<<dim3(64, 64, 3), 256, 0, stream>>>(Wq, Wk, Wv, Wt);
  rope_table_kernel<<<2048, 64, 0, stream>>>(cosT, sinT);
  lambda_kernel<<<1, 64, 0, stream>>>(lq1, lk1, lq2, lk2, lam);
  gemm_qkv_kernel<<<dim3(512, 3), 256, 0, stream>>>(Xb, Wt, cosT, sinT, scl, Qp, Kp, Vg);
  v_transpose_kernel<<<dim3(64, 8, 16), 256, 0, stream>>>(Vg, Vt);
  attn_kernel<<<512, 256, 0, stream>>>(Qp, Kp, Vt, Y1, Y2);
  combine_kernel<<<4096, 256, 0, stream>>>(Y1, Y2, lam, out);
}